// Round 4
// baseline (1604.917 us; speedup 1.0000x reference)
//
#include <hip/hip_runtime.h>
#include <hip/hip_bf16.h>

typedef unsigned short u16;
typedef unsigned int u32;

#define NNODES 10000
#define NEDGES 160000

#define C110 0.57735026918962576f
#define C111 0.70710678118654752f

// ---- module-owned scratch (~5.7 MB) ----
__device__ int   g_isf32;
__device__ float g_q[NNODES * 40];
__device__ float g_x[NNODES * 40];
__device__ float g_attn[NEDGES];
__device__ u32   g_m[NNODES];
__device__ float g_den[NNODES];
__device__ float g_upd[NNODES * 40];
__device__ float g_stats[40];
__device__ float g_par[40];
__device__ float g_w1k[1024], g_b1k[32], g_w2tk[640 * 32], g_b2k[640];
__device__ float g_w1v[1024], g_b1v[32], g_w2tv[640 * 32], g_b2v[640];

__device__ __forceinline__ float bf2f(u16 v) {
    return __uint_as_float(((u32)v) << 16);
}
__device__ __forceinline__ u32 f2bfbits(float f) {  // RNE
    u32 u = __float_as_uint(f);
    u32 r = 0x7FFFu + ((u >> 16) & 1u);
    return (u + r) >> 16;
}
__device__ __forceinline__ u32 pack2(float a, float b) {
    return f2bfbits(a) | (f2bfbits(b) << 16);
}
// ordered-uint encoding of float for atomicMax
__device__ __forceinline__ u32 encf(float f) {
    u32 u = __float_as_uint(f);
    return (u & 0x80000000u) ? ~u : (u | 0x80000000u);
}
__device__ __forceinline__ float decf(u32 u) {
    return (u & 0x80000000u) ? __uint_as_float(u & 0x7FFFFFFFu) : __uint_as_float(~u);
}

// dtype-dispatched scalar load: element i of a float tensor
__device__ __forceinline__ float ldx(const void* p, size_t i, int f32) {
    return f32 ? ((const float*)p)[i] : bf2f(((const u16*)p)[i]);
}

__device__ __forceinline__ float dot32(const float* __restrict__ w, const float (&h)[32]) {
    float s0 = 0.f, s1 = 0.f, s2 = 0.f, s3 = 0.f;
    #pragma unroll
    for (int t = 0; t < 8; ++t) {
        float4 w4 = ((const float4*)w)[t];
        s0 = fmaf(h[4*t+0], w4.x, s0);
        s1 = fmaf(h[4*t+1], w4.y, s1);
        s2 = fmaf(h[4*t+2], w4.z, s2);
        s3 = fmaf(h[4*t+3], w4.w, s3);
    }
    return (s0 + s1) + (s2 + s3);
}

// ---- dtype sniffer: even-indexed bf16 halves of f32 data are ~31% plausible ----
__global__ void k_sniff(const u16* __restrict__ atom16) {
    if (threadIdx.x != 0 || blockIdx.x != 0) return;
    int even_ok = 0;
    for (int i = 0; i < 1024; ++i) {
        float ve = bf2f(atom16[2 * i]);
        float ae = fabsf(ve);
        if (ve == 0.f || (ae > 9.3e-13f && ae < 1.1e12f)) even_ok++;
    }
    g_isf32 = (even_ok < 716) ? 1 : 0;   // <70% plausible => inputs are float32
}

// ---- init scratch (fresh every call) ----
__global__ __launch_bounds__(256) void k_init() {
    int i = blockIdx.x * 256 + threadIdx.x;
    if (i < NNODES * 40) g_upd[i] = 0.f;
    if (i < NNODES) {
        g_den[i] = 0.f;
        g_m[i] = 0x007FFFFFu;  // encf(-inf)
    }
    if (i < 40) g_stats[i] = 0.f;
}

// ---- convert/transpose weights to fp32 globals ----
__global__ __launch_bounds__(256) void k_prep(
    const void* __restrict__ kw1, const void* __restrict__ kb1,
    const void* __restrict__ kw2, const void* __restrict__ kb2,
    const void* __restrict__ vw1, const void* __restrict__ vb1,
    const void* __restrict__ vw2, const void* __restrict__ vb2) {
    const int f32 = g_isf32;
    int t = blockIdx.x * 256 + threadIdx.x;
    if (t < 640 * 32) {                 // W2T[j][t] = W2[t][j]
        int j = t >> 5, s = t & 31;
        g_w2tk[t] = ldx(kw2, s * 640 + j, f32);
        g_w2tv[t] = ldx(vw2, s * 640 + j, f32);
    }
    if (t < 1024) { g_w1k[t] = ldx(kw1, t, f32); g_w1v[t] = ldx(vw1, t, f32); }
    if (t < 640)  { g_b2k[t] = ldx(kb2, t, f32); g_b2v[t] = ldx(vb2, t, f32); }
    if (t < 32)   { g_b1k[t] = ldx(kb1, t, f32); g_b1v[t] = ldx(vb1, t, f32); }
}

// ---- q = irreps_linear(atom_features) per node ----
__global__ __launch_bounds__(256) void k_q(
    const void* __restrict__ atom, const void* __restrict__ Wqs,
    const void* __restrict__ Wqv) {
    const int f32 = g_isf32;
    int n = blockIdx.x * 256 + threadIdx.x;
    if (n >= NNODES) return;
    const size_t ab = (size_t)n * 40;
    float qs[16];
    #pragma unroll
    for (int o = 0; o < 16; ++o) qs[o] = 0.f;
    #pragma unroll 1
    for (int i = 0; i < 16; ++i) {
        float ai = ldx(atom, ab + i, f32);
        #pragma unroll
        for (int o = 0; o < 16; ++o)
            qs[o] = fmaf(ai, ldx(Wqs, i * 16 + o, f32), qs[o]);
    }
    float qv[24];
    #pragma unroll
    for (int k = 0; k < 24; ++k) qv[k] = 0.f;
    #pragma unroll 1
    for (int i = 0; i < 8; ++i) {
        float a0 = ldx(atom, ab + 16 + 3*i + 0, f32);
        float a1 = ldx(atom, ab + 16 + 3*i + 1, f32);
        float a2 = ldx(atom, ab + 16 + 3*i + 2, f32);
        #pragma unroll
        for (int o = 0; o < 8; ++o) {
            float wv = ldx(Wqv, i * 8 + o, f32);
            qv[o*3+0] = fmaf(a0, wv, qv[o*3+0]);
            qv[o*3+1] = fmaf(a1, wv, qv[o*3+1]);
            qv[o*3+2] = fmaf(a2, wv, qv[o*3+2]);
        }
    }
    float* qp = g_q + (size_t)n * 40;
    #pragma unroll
    for (int o = 0; o < 16; ++o) qp[o] = qs[o];
    #pragma unroll
    for (int k = 0; k < 24; ++k) qp[16 + k] = qv[k];
}

// h = relu(ef_row @ W1 + B1)
__device__ __forceinline__ void mlp1(const void* __restrict__ ef, size_t ebase, int f32,
                                     const float* __restrict__ W1,
                                     const float* __restrict__ B1,
                                     float (&h)[32]) {
    #pragma unroll
    for (int t = 0; t < 32; ++t) h[t] = B1[t];
    #pragma unroll 1
    for (int s = 0; s < 32; ++s) {
        const float efs = ldx(ef, ebase + s, f32);
        const float4* wr = (const float4*)(W1 + s * 32);
        #pragma unroll
        for (int t4 = 0; t4 < 8; ++t4) {
            float4 w4 = wr[t4];
            h[t4*4+0] = fmaf(efs, w4.x, h[t4*4+0]);
            h[t4*4+1] = fmaf(efs, w4.y, h[t4*4+1]);
            h[t4*4+2] = fmaf(efs, w4.z, h[t4*4+2]);
            h[t4*4+3] = fmaf(efs, w4.w, h[t4*4+3]);
        }
    }
    #pragma unroll
    for (int t = 0; t < 32; ++t) h[t] = fmaxf(h[t], 0.f);
}

// full tensor-product: per-edge weights wk[j] = B2[j] + h . W2T[j]
__device__ __forceinline__ void tp40(const float* __restrict__ W2T,
                                     const float* __restrict__ B2,
                                     const float (&h)[32], const float* xl,
                                     float sh_s, float sv0, float sv1, float sv2,
                                     float (&acc_s)[16], float (&acc_v)[24]) {
    #pragma unroll
    for (int o = 0; o < 16; ++o) acc_s[o] = 0.f;
    #pragma unroll
    for (int o = 0; o < 24; ++o) acc_v[o] = 0.f;
    const float* w = W2T;
    const float* b = B2;
    // block1: w1[i,o] * (x_s[i]*sh_s) -> out_s
    #pragma unroll 1
    for (int i = 0; i < 16; ++i) {
        const float xi = xl[i] * sh_s;
        #pragma unroll
        for (int o = 0; o < 16; ++o) {
            const float wk = b[o] + dot32(w + o * 32, h);
            acc_s[o] = fmaf(wk, xi, acc_s[o]);
        }
        w += 16 * 32; b += 16;
    }
    // block2: C110 * w2[i,o] * dot(x_v[i], sh_v) -> out_s
    #pragma unroll 1
    for (int i = 0; i < 8; ++i) {
        const float di = C110 * (xl[16+3*i]*sv0 + xl[16+3*i+1]*sv1 + xl[16+3*i+2]*sv2);
        #pragma unroll
        for (int o = 0; o < 16; ++o) {
            const float wk = b[o] + dot32(w + o * 32, h);
            acc_s[o] = fmaf(wk, di, acc_s[o]);
        }
        w += 16 * 32; b += 16;
    }
    // block3: w3[i,o] * x_s[i] (then outer-prod sh_v) -> out_v
    float t3[8];
    #pragma unroll
    for (int o = 0; o < 8; ++o) t3[o] = 0.f;
    #pragma unroll 1
    for (int i = 0; i < 16; ++i) {
        const float xi = xl[i];
        #pragma unroll
        for (int o = 0; o < 8; ++o) {
            const float wk = b[o] + dot32(w + o * 32, h);
            t3[o] = fmaf(wk, xi, t3[o]);
        }
        w += 8 * 32; b += 8;
    }
    #pragma unroll
    for (int o = 0; o < 8; ++o) {
        acc_v[o*3+0] = fmaf(t3[o], sv0, acc_v[o*3+0]);
        acc_v[o*3+1] = fmaf(t3[o], sv1, acc_v[o*3+1]);
        acc_v[o*3+2] = fmaf(t3[o], sv2, acc_v[o*3+2]);
    }
    // block4: w4[i,o] * x_v[i,:]*sh_s -> out_v
    #pragma unroll 1
    for (int i = 0; i < 8; ++i) {
        const float l0 = xl[16+3*i+0] * sh_s;
        const float l1 = xl[16+3*i+1] * sh_s;
        const float l2 = xl[16+3*i+2] * sh_s;
        #pragma unroll
        for (int o = 0; o < 8; ++o) {
            const float wk = b[o] + dot32(w + o * 32, h);
            acc_v[o*3+0] = fmaf(wk, l0, acc_v[o*3+0]);
            acc_v[o*3+1] = fmaf(wk, l1, acc_v[o*3+1]);
            acc_v[o*3+2] = fmaf(wk, l2, acc_v[o*3+2]);
        }
        w += 8 * 32; b += 8;
    }
    // block5: C111 * w5[i,o] * cross(x_v[i], sh_v) -> out_v
    #pragma unroll 1
    for (int i = 0; i < 8; ++i) {
        const float a0 = xl[16+3*i+0], a1 = xl[16+3*i+1], a2 = xl[16+3*i+2];
        const float c0 = C111 * (a1 * sv2 - a2 * sv1);
        const float c1 = C111 * (a2 * sv0 - a0 * sv2);
        const float c2 = C111 * (a0 * sv1 - a1 * sv0);
        #pragma unroll
        for (int o = 0; o < 8; ++o) {
            const float wk = b[o] + dot32(w + o * 32, h);
            acc_v[o*3+0] = fmaf(wk, c0, acc_v[o*3+0]);
            acc_v[o*3+1] = fmaf(wk, c1, acc_v[o*3+1]);
            acc_v[o*3+2] = fmaf(wk, c2, acc_v[o*3+2]);
        }
        w += 8 * 32; b += 8;
    }
}

// ---- attn pass: k-MLP -> TP -> attn[e], atomicMax m[src] ----
__global__ __launch_bounds__(256) void k_attn(
    const void* __restrict__ atom, const void* __restrict__ ef,
    const void* __restrict__ sh, const int* __restrict__ ei) {
    __shared__ float xls[256 * 41];   // stride 41 -> conflict-light runtime indexing
    const int f32 = g_isf32;
    const int e = blockIdx.x * 256 + threadIdx.x;
    if (e >= NEDGES) return;
    const int dst = ei[e];
    const int src = ei[NEDGES + e];
    float* xl = xls + threadIdx.x * 41;

    const float sh_s = ldx(sh, (size_t)e * 4 + 0, f32);
    const float sv0  = ldx(sh, (size_t)e * 4 + 1, f32);
    const float sv1  = ldx(sh, (size_t)e * 4 + 2, f32);
    const float sv2  = ldx(sh, (size_t)e * 4 + 3, f32);
    #pragma unroll 1
    for (int c = 0; c < 40; ++c) xl[c] = ldx(atom, (size_t)dst * 40 + c, f32);

    float h[32];
    mlp1(ef, (size_t)e * 32, f32, g_w1k, g_b1k, h);

    float acc_s[16], acc_v[24];
    tp40(g_w2tk, g_b2k, h, xl, sh_s, sv0, sv1, sv2, acc_s, acc_v);

    // attn = q[src] . k
    const float4* qp = (const float4*)(g_q + (size_t)src * 40);
    float at = 0.f;
    #pragma unroll
    for (int c = 0; c < 4; ++c) {
        float4 qq = qp[c];
        at = fmaf(qq.x, acc_s[c*4+0], at);
        at = fmaf(qq.y, acc_s[c*4+1], at);
        at = fmaf(qq.z, acc_s[c*4+2], at);
        at = fmaf(qq.w, acc_s[c*4+3], at);
    }
    #pragma unroll
    for (int c = 0; c < 6; ++c) {
        float4 qq = qp[4 + c];
        at = fmaf(qq.x, acc_v[c*4+0], at);
        at = fmaf(qq.y, acc_v[c*4+1], at);
        at = fmaf(qq.z, acc_v[c*4+2], at);
        at = fmaf(qq.w, acc_v[c*4+3], at);
    }
    g_attn[e] = at;
    atomicMax(g_m + src, encf(at));
}

// ---- value pass: v-MLP -> TP -> pex-weighted scatter ----
__global__ __launch_bounds__(256) void k_val(
    const void* __restrict__ atom, const void* __restrict__ ef,
    const void* __restrict__ sh, const int* __restrict__ ei) {
    __shared__ float xls[256 * 41];
    const int f32 = g_isf32;
    const int e = blockIdx.x * 256 + threadIdx.x;
    if (e >= NEDGES) return;
    const int dst = ei[e];
    const int src = ei[NEDGES + e];
    float* xl = xls + threadIdx.x * 41;

    const float sh_s = ldx(sh, (size_t)e * 4 + 0, f32);
    const float sv0  = ldx(sh, (size_t)e * 4 + 1, f32);
    const float sv1  = ldx(sh, (size_t)e * 4 + 2, f32);
    const float sv2  = ldx(sh, (size_t)e * 4 + 3, f32);
    #pragma unroll 1
    for (int c = 0; c < 40; ++c) xl[c] = ldx(atom, (size_t)dst * 40 + c, f32);

    float h[32];
    mlp1(ef, (size_t)e * 32, f32, g_w1v, g_b1v, h);

    float acc_s[16], acc_v[24];
    tp40(g_w2tv, g_b2v, h, xl, sh_s, sv0, sv1, sv2, acc_s, acc_v);

    const float m = decf(g_m[src]);
    // fminf squashes NaN and enforces attn<=m invariant
    const float pex = expf(fminf(g_attn[e] - m, 0.f));
    atomicAdd(g_den + src, pex);
    float* up = g_upd + (size_t)src * 40;
    #pragma unroll
    for (int o = 0; o < 16; ++o) atomicAdd(up + o, acc_s[o] * pex);
    #pragma unroll
    for (int o = 0; o < 24; ++o) atomicAdd(up + 16 + o, acc_v[o] * pex);
}

// ---- x = atom + upd/den ; accumulate batchnorm stats ----
__global__ __launch_bounds__(256) void k_stats(const void* __restrict__ atom) {
    const int f32 = g_isf32;
    int n = blockIdx.x * 256 + threadIdx.x;
    bool act = n < NNODES;
    float x[40];
    #pragma unroll
    for (int c = 0; c < 40; ++c) x[c] = 0.f;
    if (act) {
        float den = g_den[n];
        float inv = (den > 0.f) ? 1.f / den : 0.f;
        const float4* up = (const float4*)(g_upd + (size_t)n * 40);
        float4* xp = (float4*)(g_x + (size_t)n * 40);
        #pragma unroll 1
        for (int c = 0; c < 40; ++c) x[c] = ldx(atom, (size_t)n * 40 + c, f32);
        #pragma unroll
        for (int c = 0; c < 10; ++c) {
            float4 u = up[c];
            float4 r = make_float4(x[c*4+0] + u.x * inv, x[c*4+1] + u.y * inv,
                                   x[c*4+2] + u.z * inv, x[c*4+3] + u.w * inv);
            x[c*4+0] = r.x; x[c*4+1] = r.y; x[c*4+2] = r.z; x[c*4+3] = r.w;
            xp[c] = r;
        }
    }
    float st[40];
    #pragma unroll
    for (int c = 0; c < 16; ++c) st[c] = x[c];
    #pragma unroll
    for (int c = 0; c < 16; ++c) st[16 + c] = x[c] * x[c];
    #pragma unroll
    for (int i = 0; i < 8; ++i) {
        float a0 = x[16+3*i+0], a1 = x[16+3*i+1], a2 = x[16+3*i+2];
        st[32 + i] = a0*a0 + a1*a1 + a2*a2;
    }
    #pragma unroll
    for (int c = 0; c < 40; ++c) {
        float v = st[c];
        v += __shfl_xor(v, 1);  v += __shfl_xor(v, 2);  v += __shfl_xor(v, 4);
        v += __shfl_xor(v, 8);  v += __shfl_xor(v, 16); v += __shfl_xor(v, 32);
        st[c] = v;
    }
    if ((threadIdx.x & 63) == 0) {
        #pragma unroll
        for (int c = 0; c < 40; ++c) atomicAdd(g_stats + c, st[c]);
    }
}

// ---- finalize batchnorm scale/shift ----
__global__ void k_final(const void* __restrict__ bws, const void* __restrict__ bbs,
                        const void* __restrict__ bwv) {
    const int f32 = g_isf32;
    int t = threadIdx.x;
    const float invN = 1.f / (float)NNODES;
    if (t < 16) {
        float mu = g_stats[t] * invN;
        float var = fmaxf(g_stats[16 + t] * invN - mu * mu, 0.f);
        float isd = 1.f / sqrtf(var + 1e-5f);
        float sc = ldx(bws, t, f32) * isd;
        g_par[t] = sc;
        g_par[16 + t] = ldx(bbs, t, f32) - mu * sc;
    } else if (t >= 32 && t < 40) {
        int i = t - 32;
        float norm = g_stats[32 + i] * (invN / 3.f);
        g_par[32 + i] = ldx(bwv, i, f32) / sqrtf(norm + 1e-5f);
    }
}

// ---- apply batchnorm, emit output part 0 in the sniffed dtype ----
__global__ __launch_bounds__(256) void k_out(void* __restrict__ out) {
    const int f32 = g_isf32;
    int n = blockIdx.x * 256 + threadIdx.x;
    if (n >= NNODES) return;
    const float* xp = g_x + (size_t)n * 40;
    float res[40];
    #pragma unroll
    for (int c = 0; c < 16; ++c) res[c] = xp[c] * g_par[c] + g_par[16 + c];
    #pragma unroll
    for (int i = 0; i < 8; ++i) {
        float s = g_par[32 + i];
        res[16+3*i+0] = xp[16+3*i+0] * s;
        res[16+3*i+1] = xp[16+3*i+1] * s;
        res[16+3*i+2] = xp[16+3*i+2] * s;
    }
    if (f32) {
        float* op = (float*)out + (size_t)n * 40;
        #pragma unroll
        for (int c = 0; c < 40; ++c) op[c] = res[c];
    } else {
        uint4* op = (uint4*)((u16*)out + (size_t)n * 40);
        #pragma unroll
        for (int c = 0; c < 5; ++c) {
            uint4 r;
            r.x = pack2(res[c*8+0], res[c*8+1]);
            r.y = pack2(res[c*8+2], res[c*8+3]);
            r.z = pack2(res[c*8+4], res[c*8+5]);
            r.w = pack2(res[c*8+6], res[c*8+7]);
            op[c] = r;
        }
    }
}

// ---- passthrough copy of edge_features into output part 1 (bit-exact) ----
__global__ __launch_bounds__(256) void k_copy(const char* __restrict__ src, char* __restrict__ outBase) {
    const int f32 = g_isf32;
    const size_t n16 = f32 ? 1280000u : 640000u;           // 5,120,000 elems * (4|2) B / 16
    const uint4* s = (const uint4*)src;
    uint4* d = (uint4*)(outBase + (f32 ? 1600000u : 800000u)); // 400,000 elems * (4|2) B
    for (size_t i = blockIdx.x * 256u + threadIdx.x; i < n16; i += (size_t)gridDim.x * 256u)
        d[i] = s[i];
}

extern "C" void kernel_launch(void* const* d_in, const int* in_sizes, int n_in,
                              void* d_out, int out_size, void* d_ws, size_t ws_size,
                              hipStream_t stream) {
    const void* atom = d_in[0];
    const void* ef   = d_in[1];
    const void* sh   = d_in[2];
    const void* Wqs  = d_in[3];
    const void* Wqv  = d_in[4];
    const void* kw1  = d_in[5];
    const void* kb1  = d_in[6];
    const void* kw2  = d_in[7];
    const void* kb2  = d_in[8];
    const void* vw1  = d_in[9];
    const void* vb1  = d_in[10];
    const void* vw2  = d_in[11];
    const void* vb2  = d_in[12];
    const void* bws  = d_in[13];
    const void* bbs  = d_in[14];
    const void* bwv  = d_in[15];
    const int*  ei   = (const int*)d_in[16];

    k_sniff<<<1, 64, 0, stream>>>((const u16*)atom);
    k_init<<<1563, 256, 0, stream>>>();
    k_prep<<<80, 256, 0, stream>>>(kw1, kb1, kw2, kb2, vw1, vb1, vw2, vb2);
    k_q<<<40, 256, 0, stream>>>(atom, Wqs, Wqv);
    k_attn<<<625, 256, 0, stream>>>(atom, ef, sh, ei);
    k_val<<<625, 256, 0, stream>>>(atom, ef, sh, ei);
    k_stats<<<40, 256, 0, stream>>>(atom);
    k_final<<<1, 64, 0, stream>>>(bws, bbs, bwv);
    k_out<<<40, 256, 0, stream>>>(d_out);
    k_copy<<<2500, 256, 0, stream>>>((const char*)ef, (char*)d_out);
}

// Round 6
// 738.981 us; speedup vs baseline: 2.1718x; 2.1718x over previous
//
#include <hip/hip_runtime.h>
#include <hip/hip_bf16.h>

typedef unsigned short u16;
typedef unsigned int u32;

#define NNODES 10000
#define NEDGES 160000

#define C110 0.57735026918962576f
#define C111 0.70710678118654752f

typedef __attribute__((ext_vector_type(8))) short short8;
typedef __attribute__((ext_vector_type(4))) float f32x4;

// ---- module-owned scratch ----
__device__ int   g_isf32;
__device__ float g_q[NNODES * 40];
__device__ float g_x[NNODES * 40];
__device__ float g_attn[NEDGES];
__device__ u32   g_m[NNODES];
__device__ float g_den[NNODES];
__device__ float g_upd[NNODES * 40];
__device__ float g_stats[40];
__device__ float g_par[40];
__device__ float g_vbuf[(size_t)NEDGES * 40];   // per-edge raw v rows (25.6 MB)
__device__ u32   g_deg[NNODES], g_cur[NNODES], g_off[NNODES + 1];
__device__ int   g_csr[NEDGES];
// split-bf16 weights: hi + lo residual. W1T[t][s], W2T[n][k]; biases f32
__device__ u16   g_w1hk[32 * 32], g_w1lk[32 * 32], g_w1hv[32 * 32], g_w1lv[32 * 32];
__device__ u16   g_w2hk[640 * 32], g_w2lk[640 * 32], g_w2hv[640 * 32], g_w2lv[640 * 32];
__device__ float g_b1k[32], g_b1v[32], g_b2k[640], g_b2v[640];

__device__ __forceinline__ float bf2f(u16 v) {
    return __uint_as_float(((u32)v) << 16);
}
__device__ __forceinline__ u32 f2bfbits(float f) {  // RNE
    u32 u = __float_as_uint(f);
    u32 r = 0x7FFFu + ((u >> 16) & 1u);
    return (u + r) >> 16;
}
__device__ __forceinline__ u32 pack2(float a, float b) {
    return f2bfbits(a) | (f2bfbits(b) << 16);
}
__device__ __forceinline__ u32 encf(float f) {
    u32 u = __float_as_uint(f);
    return (u & 0x80000000u) ? ~u : (u | 0x80000000u);
}
__device__ __forceinline__ float decf(u32 u) {
    return (u & 0x80000000u) ? __uint_as_float(u & 0x7FFFFFFFu) : __uint_as_float(~u);
}
__device__ __forceinline__ float ldx(const void* p, size_t i, int f32) {
    return f32 ? ((const float*)p)[i] : bf2f(((const u16*)p)[i]);
}
// split f32 -> (hi bf16 bits, lo bf16 bits)
__device__ __forceinline__ void split2(float v, u16& hi, u16& lo) {
    hi = (u16)f2bfbits(v);
    lo = (u16)f2bfbits(v - bf2f(hi));
}

// ---- dtype sniffer (proved f32 in R4; kept for robustness) ----
__global__ void k_sniff(const u16* __restrict__ atom16) {
    if (threadIdx.x != 0 || blockIdx.x != 0) return;
    int even_ok = 0;
    for (int i = 0; i < 1024; ++i) {
        float ve = bf2f(atom16[2 * i]);
        float ae = fabsf(ve);
        if (ve == 0.f || (ae > 9.3e-13f && ae < 1.1e12f)) even_ok++;
    }
    g_isf32 = (even_ok < 716) ? 1 : 0;
}

// ---- init (fresh every call) ----
__global__ __launch_bounds__(256) void k_init() {
    int i = blockIdx.x * 256 + threadIdx.x;
    if (i < NNODES) {
        g_deg[i] = 0u;
        g_m[i] = 0x007FFFFFu;  // encf(-inf)
    }
    if (i < 40) g_stats[i] = 0.f;
}

// ---- weights -> split-bf16 transposed layouts + f32 biases ----
__global__ __launch_bounds__(256) void k_prep(
    const void* __restrict__ kw1, const void* __restrict__ kb1,
    const void* __restrict__ kw2, const void* __restrict__ kb2,
    const void* __restrict__ vw1, const void* __restrict__ vb1,
    const void* __restrict__ vw2, const void* __restrict__ vb2) {
    const int f32 = g_isf32;
    int t = blockIdx.x * 256 + threadIdx.x;
    if (t < 640 * 32) {               // W2T[n][k] = W2[k][n]
        int n = t >> 5, k = t & 31;
        split2(ldx(kw2, (size_t)k * 640 + n, f32), g_w2hk[t], g_w2lk[t]);
        split2(ldx(vw2, (size_t)k * 640 + n, f32), g_w2hv[t], g_w2lv[t]);
    }
    if (t < 1024) {                   // W1T[tt][s] = W1[s][tt]
        int tt = t >> 5, s = t & 31;
        split2(ldx(kw1, (size_t)s * 32 + tt, f32), g_w1hk[t], g_w1lk[t]);
        split2(ldx(vw1, (size_t)s * 32 + tt, f32), g_w1hv[t], g_w1lv[t]);
    }
    if (t < 640) { g_b2k[t] = ldx(kb2, t, f32); g_b2v[t] = ldx(vb2, t, f32); }
    if (t < 32)  { g_b1k[t] = ldx(kb1, t, f32); g_b1v[t] = ldx(vb1, t, f32); }
}

// ---- q = irreps_linear(atom) per node (fp32; small) ----
__global__ __launch_bounds__(256) void k_q(
    const void* __restrict__ atom, const void* __restrict__ Wqs,
    const void* __restrict__ Wqv) {
    const int f32 = g_isf32;
    int n = blockIdx.x * 256 + threadIdx.x;
    if (n >= NNODES) return;
    const size_t ab = (size_t)n * 40;
    float qs[16];
    #pragma unroll
    for (int o = 0; o < 16; ++o) qs[o] = 0.f;
    #pragma unroll 1
    for (int i = 0; i < 16; ++i) {
        float ai = ldx(atom, ab + i, f32);
        #pragma unroll
        for (int o = 0; o < 16; ++o)
            qs[o] = fmaf(ai, ldx(Wqs, i * 16 + o, f32), qs[o]);
    }
    float qv[24];
    #pragma unroll
    for (int k = 0; k < 24; ++k) qv[k] = 0.f;
    #pragma unroll 1
    for (int i = 0; i < 8; ++i) {
        float a0 = ldx(atom, ab + 16 + 3*i + 0, f32);
        float a1 = ldx(atom, ab + 16 + 3*i + 1, f32);
        float a2 = ldx(atom, ab + 16 + 3*i + 2, f32);
        #pragma unroll
        for (int o = 0; o < 8; ++o) {
            float wv = ldx(Wqv, i * 8 + o, f32);
            qv[o*3+0] = fmaf(a0, wv, qv[o*3+0]);
            qv[o*3+1] = fmaf(a1, wv, qv[o*3+1]);
            qv[o*3+2] = fmaf(a2, wv, qv[o*3+2]);
        }
    }
    float* qp = g_q + (size_t)n * 40;
    #pragma unroll
    for (int o = 0; o < 16; ++o) qp[o] = qs[o];
    #pragma unroll
    for (int k = 0; k < 24; ++k) qp[16 + k] = qv[k];
}

// ---- CSR build ----
__global__ __launch_bounds__(256) void k_deg(const int* __restrict__ ei) {
    int e = blockIdx.x * 256 + threadIdx.x;
    if (e < NEDGES) atomicAdd(&g_deg[ei[NEDGES + e]], 1u);
}
__global__ __launch_bounds__(256) void k_scan() {
    __shared__ u32 part[256];
    int t = threadIdx.x;
    int lo = t * 40, hi = lo + 40; if (hi > NNODES) hi = NNODES; if (lo > NNODES) lo = NNODES;
    u32 s = 0;
    for (int i = lo; i < hi; ++i) s += g_deg[i];
    part[t] = s;
    __syncthreads();
    if (t == 0) {
        u32 run = 0;
        for (int i = 0; i < 256; ++i) { u32 v = part[i]; part[i] = run; run += v; }
    }
    __syncthreads();
    u32 run = part[t];
    for (int i = lo; i < hi; ++i) { g_off[i] = run; g_cur[i] = run; run += g_deg[i]; }
    if (t == 255) g_off[NNODES] = NEDGES;
}
__global__ __launch_bounds__(256) void k_fill(const int* __restrict__ ei) {
    int e = blockIdx.x * 256 + threadIdx.x;
    if (e < NEDGES) {
        u32 p = atomicAdd(&g_cur[ei[NEDGES + e]], 1u);
        g_csr[p] = e;
    }
}

// ================= fused edge kernel: split-bf16 MFMA MLP + TP =================
// PASS 0: k-path -> attn + atomicMax ; PASS 1: v-path -> g_vbuf
#define A1S 40    // LDS row stride in shorts (80 B, 16B-aligned)
#define ACCS 42   // accbuf row stride in floats

// C = Ah*Bh + Ah*Bl + Al*Bh  (~fp32-accurate product of split operands)
__device__ __forceinline__ f32x4 mfma3(short8 ah, short8 al, short8 bh, short8 bl) {
    f32x4 acc = {0.f, 0.f, 0.f, 0.f};
    acc = __builtin_amdgcn_mfma_f32_16x16x32_bf16(al, bh, acc, 0, 0, 0);
    acc = __builtin_amdgcn_mfma_f32_16x16x32_bf16(ah, bl, acc, 0, 0, 0);
    acc = __builtin_amdgcn_mfma_f32_16x16x32_bf16(ah, bh, acc, 0, 0, 0);
    return acc;
}

template<int PASS>
__global__ __launch_bounds__(256) void k_edge(
    const void* __restrict__ atom, const void* __restrict__ ef,
    const void* __restrict__ sh, const int* __restrict__ ei) {
    __shared__ __align__(16) float smF[91 * 64];       // TP factor table [row][edge]
    __shared__ __align__(16) u16   smA1h[64 * A1S];    // EF hi bf16 [edge][32]
    __shared__ __align__(16) u16   smA1l[64 * A1S];    // EF lo
    __shared__ __align__(16) u16   smA2h[64 * A1S];    // H hi bf16 [edge][32]
    __shared__ __align__(16) u16   smA2l[64 * A1S];    // H lo
    __shared__ __align__(16) float smAcc[64 * ACCS];   // per-edge out accum [edge][40]

    const int f32 = g_isf32;
    const int t = threadIdx.x;
    const int w = t >> 6, lane = t & 63;
    const int quad = lane >> 4, c = lane & 15;
    const int eb = blockIdx.x * 64;

    const u16* w1h = PASS ? g_w1hv : g_w1hk;
    const u16* w1l = PASS ? g_w1lv : g_w1lk;
    const u16* w2h = PASS ? g_w2hv : g_w2hk;
    const u16* w2l = PASS ? g_w2lv : g_w2lk;
    const float* b1 = PASS ? g_b1v : g_b1k;
    const float* b2 = PASS ? g_b2v : g_b2k;

    // ---------- staging ----------
    if (w == 0) {                       // x row -> factor table
        const int e = lane;
        const int ge = eb + e;
        const int dst = ei[ge];
        float x[40];
        #pragma unroll
        for (int i = 0; i < 40; ++i) x[i] = ldx(atom, (size_t)dst * 40 + i, f32);
        const float ss = ldx(sh, (size_t)ge * 4 + 0, f32);
        const float s0 = ldx(sh, (size_t)ge * 4 + 1, f32);
        const float s1 = ldx(sh, (size_t)ge * 4 + 2, f32);
        const float s2 = ldx(sh, (size_t)ge * 4 + 3, f32);
        #pragma unroll
        for (int i = 0; i < 16; ++i) {
            smF[(0 + i) * 64 + e] = x[i] * ss;       // fb1
            smF[(24 + i) * 64 + e] = x[i];           // fb3
        }
        #pragma unroll
        for (int i = 0; i < 8; ++i) {
            float a0 = x[16 + 3*i], a1 = x[17 + 3*i], a2 = x[18 + 3*i];
            smF[(16 + i) * 64 + e] = C110 * (a0*s0 + a1*s1 + a2*s2);   // fb2
            smF[(40 + i) * 64 + e] = a0 * ss;                          // fb4 d=0
            smF[(48 + i) * 64 + e] = a1 * ss;
            smF[(56 + i) * 64 + e] = a2 * ss;
            smF[(64 + i) * 64 + e] = C111 * (a1*s2 - a2*s1);           // fb5 d=0
            smF[(72 + i) * 64 + e] = C111 * (a2*s0 - a0*s2);
            smF[(80 + i) * 64 + e] = C111 * (a0*s1 - a1*s0);
        }
        smF[88 * 64 + e] = s0; smF[89 * 64 + e] = s1; smF[90 * 64 + e] = s2;
    } else if (w == 1) {                // EF row -> split bf16 A1
        const int e = lane;
        const size_t base = (size_t)(eb + e) * 32;
        u32* dh = (u32*)(smA1h + e * A1S);
        u32* dl = (u32*)(smA1l + e * A1S);
        #pragma unroll
        for (int kk = 0; kk < 16; ++kk) {
            float v0 = ldx(ef, base + 2*kk, f32);
            float v1 = ldx(ef, base + 2*kk + 1, f32);
            u16 h0, l0, h1, l1;
            split2(v0, h0, l0); split2(v1, h1, l1);
            dh[kk] = (u32)h0 | ((u32)h1 << 16);
            dl[kk] = (u32)l0 | ((u32)l1 << 16);
        }
    } else if (w == 2) {                // zero accbuf
        for (int i = lane; i < 64 * ACCS; i += 64) smAcc[i] = 0.f;
    }
    __syncthreads();

    // ---------- GEMM1: H = relu(EF @ W1 + b1) -> split bf16 smA2 ----------
    {
        short8 ah = *(const short8*)(smA1h + (w * 16 + c) * A1S + quad * 8);
        short8 al = *(const short8*)(smA1l + (w * 16 + c) * A1S + quad * 8);
        #pragma unroll
        for (int nt = 0; nt < 2; ++nt) {
            short8 bh = *(const short8*)(w1h + ((nt * 16 + c) * 32 + quad * 8));
            short8 bl = *(const short8*)(w1l + ((nt * 16 + c) * 32 + quad * 8));
            f32x4 acc = mfma3(ah, al, bh, bl);
            float bias = b1[nt * 16 + c];
            #pragma unroll
            for (int r = 0; r < 4; ++r) {
                float hv = fmaxf(acc[r] + bias, 0.f);
                u16 hh, hl;
                split2(hv, hh, hl);
                smA2h[(w * 16 + quad * 4 + r) * A1S + nt * 16 + c] = hh;
                smA2l[(w * 16 + quad * 4 + r) * A1S + nt * 16 + c] = hl;
            }
        }
    }
    __syncthreads();

    // ---------- GEMM2 + fused TP: wave w owns cols [w*160, w*160+160) ----------
    {
        short8 bh[10], bl[10]; float b2l[10];
        #pragma unroll
        for (int nt = 0; nt < 10; ++nt) {
            int n = w * 160 + nt * 16 + c;
            bh[nt] = *(const short8*)(w2h + (n * 32 + quad * 8));
            bl[nt] = *(const short8*)(w2l + (n * 32 + quad * 8));
            b2l[nt] = b2[n];
        }
        const int o = c & 7;
        const int ch = c >> 3;
        #pragma unroll 1
        for (int mt = 0; mt < 4; ++mt) {
            short8 afh = *(const short8*)(smA2h + (mt * 16 + c) * A1S + quad * 8);
            short8 afl = *(const short8*)(smA2l + (mt * 16 + c) * A1S + quad * 8);
            const int e0 = mt * 16 + quad * 4;
            float aS[4] = {0.f, 0.f, 0.f, 0.f};
            float aT[4] = {0.f, 0.f, 0.f, 0.f};
            float aV[12] = {0.f,0.f,0.f,0.f,0.f,0.f,0.f,0.f,0.f,0.f,0.f,0.f};
            #pragma unroll
            for (int nt = 0; nt < 10; ++nt) {
                f32x4 C = mfma3(afh, afl, bh[nt], bl[nt]);
                const int jb = w * 160 + nt * 16;
                if (jb < 256) {                        // block1 -> out_s
                    f32x4 f = *(const f32x4*)(smF + (jb >> 4) * 64 + e0);
                    #pragma unroll
                    for (int r = 0; r < 4; ++r) aS[r] = fmaf(C[r] + b2l[nt], f[r], aS[r]);
                } else if (jb < 384) {                 // block2 -> out_s
                    f32x4 f = *(const f32x4*)(smF + (16 + ((jb - 256) >> 4)) * 64 + e0);
                    #pragma unroll
                    for (int r = 0; r < 4; ++r) aS[r] = fmaf(C[r] + b2l[nt], f[r], aS[r]);
                } else if (jb < 512) {                 // block3 -> t3
                    f32x4 f = *(const f32x4*)(smF + (24 + ((jb - 384) >> 3) + ch) * 64 + e0);
                    #pragma unroll
                    for (int r = 0; r < 4; ++r) aT[r] = fmaf(C[r] + b2l[nt], f[r], aT[r]);
                } else if (jb < 576) {                 // block4 -> out_v
                    const int ib = ((jb - 512) >> 3) + ch;
                    #pragma unroll
                    for (int d = 0; d < 3; ++d) {
                        f32x4 f = *(const f32x4*)(smF + (40 + d * 8 + ib) * 64 + e0);
                        #pragma unroll
                        for (int r = 0; r < 4; ++r) aV[d*4+r] = fmaf(C[r] + b2l[nt], f[r], aV[d*4+r]);
                    }
                } else {                               // block5 -> out_v
                    const int ib = ((jb - 576) >> 3) + ch;
                    #pragma unroll
                    for (int d = 0; d < 3; ++d) {
                        f32x4 f = *(const f32x4*)(smF + (64 + d * 8 + ib) * 64 + e0);
                        #pragma unroll
                        for (int r = 0; r < 4; ++r) aV[d*4+r] = fmaf(C[r] + b2l[nt], f[r], aV[d*4+r]);
                    }
                }
            }
            // flush partials into per-edge accumulator (LDS atomics)
            if (w <= 2) {
                #pragma unroll
                for (int r = 0; r < 4; ++r) atomicAdd(&smAcc[(e0 + r) * ACCS + c], aS[r]);
            }
            if (w >= 2) {
                #pragma unroll
                for (int d = 0; d < 3; ++d) {
                    f32x4 sv = *(const f32x4*)(smF + (88 + d) * 64 + e0);
                    #pragma unroll
                    for (int r = 0; r < 4; ++r)
                        atomicAdd(&smAcc[(e0 + r) * ACCS + 16 + o * 3 + d], aT[r] * sv[r]);
                }
            }
            if (w == 3) {
                #pragma unroll
                for (int d = 0; d < 3; ++d)
                    #pragma unroll
                    for (int r = 0; r < 4; ++r)
                        atomicAdd(&smAcc[(e0 + r) * ACCS + 16 + o * 3 + d], aV[d*4+r]);
            }
        }
    }
    __syncthreads();

    // ---------- epilogue ----------
    if (t < 64) {
        const int ge = eb + t;
        if (PASS == 0) {
            const int src = ei[NEDGES + ge];
            const float* qp = g_q + (size_t)src * 40;
            float at = 0.f;
            #pragma unroll
            for (int c2 = 0; c2 < 40; ++c2) at = fmaf(qp[c2], smAcc[t * ACCS + c2], at);
            g_attn[ge] = at;
            atomicMax(&g_m[src], encf(at));
        } else {
            float* vb = g_vbuf + (size_t)ge * 40;
            #pragma unroll
            for (int c2 = 0; c2 < 40; ++c2) vb[c2] = smAcc[t * ACCS + c2];
        }
    }
}

// ---- per-node softmax gather (one wave per node; no global atomics) ----
__global__ __launch_bounds__(256) void k_gather() {
    int node = blockIdx.x * 4 + (threadIdx.x >> 6);
    int lane = threadIdx.x & 63;
    if (node >= NNODES) return;
    u32 s = g_off[node], epos = g_off[node + 1];
    float m = decf(g_m[node]);
    float den = 0.f, acc = 0.f;
    for (u32 p = s; p < epos; ++p) {
        int e = g_csr[p];
        float pex = expf(fminf(g_attn[e] - m, 0.f));
        den += pex;
        if (lane < 40) acc = fmaf(pex, g_vbuf[(size_t)e * 40 + lane], acc);
    }
    if (lane < 40) g_upd[node * 40 + lane] = acc;
    if (lane == 0) g_den[node] = den;
}

// ---- x = atom + upd/den ; batchnorm stats ----
__global__ __launch_bounds__(256) void k_stats(const void* __restrict__ atom) {
    const int f32 = g_isf32;
    int n = blockIdx.x * 256 + threadIdx.x;
    bool act = n < NNODES;
    float x[40];
    #pragma unroll
    for (int c = 0; c < 40; ++c) x[c] = 0.f;
    if (act) {
        float den = g_den[n];
        float inv = (den > 0.f) ? 1.f / den : 0.f;
        const float4* up = (const float4*)(g_upd + (size_t)n * 40);
        float4* xp = (float4*)(g_x + (size_t)n * 40);
        #pragma unroll 1
        for (int c = 0; c < 40; ++c) x[c] = ldx(atom, (size_t)n * 40 + c, f32);
        #pragma unroll
        for (int c = 0; c < 10; ++c) {
            float4 u = up[c];
            float4 r = make_float4(x[c*4+0] + u.x * inv, x[c*4+1] + u.y * inv,
                                   x[c*4+2] + u.z * inv, x[c*4+3] + u.w * inv);
            x[c*4+0] = r.x; x[c*4+1] = r.y; x[c*4+2] = r.z; x[c*4+3] = r.w;
            xp[c] = r;
        }
    }
    float st[40];
    #pragma unroll
    for (int c = 0; c < 16; ++c) st[c] = x[c];
    #pragma unroll
    for (int c = 0; c < 16; ++c) st[16 + c] = x[c] * x[c];
    #pragma unroll
    for (int i = 0; i < 8; ++i) {
        float a0 = x[16+3*i+0], a1 = x[16+3*i+1], a2 = x[16+3*i+2];
        st[32 + i] = a0*a0 + a1*a1 + a2*a2;
    }
    #pragma unroll
    for (int c = 0; c < 40; ++c) {
        float v = st[c];
        v += __shfl_xor(v, 1);  v += __shfl_xor(v, 2);  v += __shfl_xor(v, 4);
        v += __shfl_xor(v, 8);  v += __shfl_xor(v, 16); v += __shfl_xor(v, 32);
        st[c] = v;
    }
    if ((threadIdx.x & 63) == 0) {
        #pragma unroll
        for (int c = 0; c < 40; ++c) atomicAdd(g_stats + c, st[c]);
    }
}

__global__ void k_final(const void* __restrict__ bws, const void* __restrict__ bbs,
                        const void* __restrict__ bwv) {
    const int f32 = g_isf32;
    int t = threadIdx.x;
    const float invN = 1.f / (float)NNODES;
    if (t < 16) {
        float mu = g_stats[t] * invN;
        float var = fmaxf(g_stats[16 + t] * invN - mu * mu, 0.f);
        float isd = 1.f / sqrtf(var + 1e-5f);
        float sc = ldx(bws, t, f32) * isd;
        g_par[t] = sc;
        g_par[16 + t] = ldx(bbs, t, f32) - mu * sc;
    } else if (t >= 32 && t < 40) {
        int i = t - 32;
        float norm = g_stats[32 + i] * (invN / 3.f);
        g_par[32 + i] = ldx(bwv, i, f32) / sqrtf(norm + 1e-5f);
    }
}

__global__ __launch_bounds__(256) void k_out(void* __restrict__ out) {
    const int f32 = g_isf32;
    int n = blockIdx.x * 256 + threadIdx.x;
    if (n >= NNODES) return;
    const float* xp = g_x + (size_t)n * 40;
    float res[40];
    #pragma unroll
    for (int c = 0; c < 16; ++c) res[c] = xp[c] * g_par[c] + g_par[16 + c];
    #pragma unroll
    for (int i = 0; i < 8; ++i) {
        float s = g_par[32 + i];
        res[16+3*i+0] = xp[16+3*i+0] * s;
        res[16+3*i+1] = xp[16+3*i+1] * s;
        res[16+3*i+2] = xp[16+3*i+2] * s;
    }
    if (f32) {
        float* op = (float*)out + (size_t)n * 40;
        #pragma unroll
        for (int c = 0; c < 40; ++c) op[c] = res[c];
    } else {
        uint4* op = (uint4*)((u16*)out + (size_t)n * 40);
        #pragma unroll
        for (int c = 0; c < 5; ++c) {
            uint4 r;
            r.x = pack2(res[c*8+0], res[c*8+1]);
            r.y = pack2(res[c*8+2], res[c*8+3]);
            r.z = pack2(res[c*8+4], res[c*8+5]);
            r.w = pack2(res[c*8+6], res[c*8+7]);
            op[c] = r;
        }
    }
}

__global__ __launch_bounds__(256) void k_copy(const char* __restrict__ src, char* __restrict__ outBase) {
    const int f32 = g_isf32;
    const size_t n16 = f32 ? 1280000u : 640000u;
    const uint4* s = (const uint4*)src;
    uint4* d = (uint4*)(outBase + (f32 ? 1600000u : 800000u));
    for (size_t i = blockIdx.x * 256u + threadIdx.x; i < n16; i += (size_t)gridDim.x * 256u)
        d[i] = s[i];
}

extern "C" void kernel_launch(void* const* d_in, const int* in_sizes, int n_in,
                              void* d_out, int out_size, void* d_ws, size_t ws_size,
                              hipStream_t stream) {
    const void* atom = d_in[0];
    const void* ef   = d_in[1];
    const void* sh   = d_in[2];
    const void* Wqs  = d_in[3];
    const void* Wqv  = d_in[4];
    const void* kw1  = d_in[5];
    const void* kb1  = d_in[6];
    const void* kw2  = d_in[7];
    const void* kb2  = d_in[8];
    const void* vw1  = d_in[9];
    const void* vb1  = d_in[10];
    const void* vw2  = d_in[11];
    const void* vb2  = d_in[12];
    const void* bws  = d_in[13];
    const void* bbs  = d_in[14];
    const void* bwv  = d_in[15];
    const int*  ei   = (const int*)d_in[16];

    k_sniff<<<1, 64, 0, stream>>>((const u16*)atom);
    k_init<<<40, 256, 0, stream>>>();
    k_prep<<<80, 256, 0, stream>>>(kw1, kb1, kw2, kb2, vw1, vb1, vw2, vb2);
    k_q<<<40, 256, 0, stream>>>(atom, Wqs, Wqv);
    k_deg<<<625, 256, 0, stream>>>(ei);
    k_scan<<<1, 256, 0, stream>>>();
    k_fill<<<625, 256, 0, stream>>>(ei);
    k_edge<0><<<2500, 256, 0, stream>>>(atom, ef, sh, ei);
    k_edge<1><<<2500, 256, 0, stream>>>(atom, ef, sh, ei);
    k_gather<<<2500, 256, 0, stream>>>();
    k_stats<<<40, 256, 0, stream>>>(atom);
    k_final<<<1, 64, 0, stream>>>(bws, bbs, bwv);
    k_out<<<40, 256, 0, stream>>>(d_out);
    k_copy<<<2500, 256, 0, stream>>>((const char*)ef, (char*)d_out);
}

// Round 7
// 444.114 us; speedup vs baseline: 3.6138x; 1.6639x over previous
//
#include <hip/hip_runtime.h>
#include <hip/hip_bf16.h>

typedef unsigned short u16;
typedef unsigned int u32;

#define NNODES 10000
#define NEDGES 160000

#define C110 0.57735026918962576f
#define C111 0.70710678118654752f

typedef __attribute__((ext_vector_type(8))) short short8;
typedef __attribute__((ext_vector_type(4))) float f32x4;

// ---- module-owned scratch ----
__device__ int   g_isf32;
__device__ float g_q[NNODES * 40];
__device__ float g_x[NNODES * 40];
__device__ float g_attn[NEDGES];
__device__ u32   g_m[NNODES];
__device__ float g_den[NNODES];
__device__ float g_upd[NNODES * 40];
__device__ float g_stats[40];
__device__ float g_par[40];
__device__ float g_vbuf[(size_t)NEDGES * 40];
__device__ u32   g_deg[NNODES], g_cur[NNODES], g_off[NNODES + 1];
__device__ int   g_csr[NEDGES];
// split-bf16 weights: hi + lo residual. W1T[t][s], W2T[n][k]; biases f32
__device__ u16   g_w1hk[32 * 32], g_w1lk[32 * 32], g_w1hv[32 * 32], g_w1lv[32 * 32];
__device__ u16   g_w2hk[640 * 32], g_w2lk[640 * 32], g_w2hv[640 * 32], g_w2lv[640 * 32];
__device__ float g_b1k[32], g_b1v[32], g_b2k[640], g_b2v[640];

__device__ __forceinline__ float bf2f(u16 v) {
    return __uint_as_float(((u32)v) << 16);
}
__device__ __forceinline__ u32 f2bfbits(float f) {  // RNE
    u32 u = __float_as_uint(f);
    u32 r = 0x7FFFu + ((u >> 16) & 1u);
    return (u + r) >> 16;
}
__device__ __forceinline__ u32 pack2(float a, float b) {
    return f2bfbits(a) | (f2bfbits(b) << 16);
}
__device__ __forceinline__ u32 encf(float f) {
    u32 u = __float_as_uint(f);
    return (u & 0x80000000u) ? ~u : (u | 0x80000000u);
}
__device__ __forceinline__ float decf(u32 u) {
    return (u & 0x80000000u) ? __uint_as_float(u & 0x7FFFFFFFu) : __uint_as_float(~u);
}
__device__ __forceinline__ float ldx(const void* p, size_t i, int f32) {
    return f32 ? ((const float*)p)[i] : bf2f(((const u16*)p)[i]);
}
__device__ __forceinline__ void split2(float v, u16& hi, u16& lo) {
    hi = (u16)f2bfbits(v);
    lo = (u16)f2bfbits(v - bf2f(hi));
}
// C = Ah*Bh + Ah*Bl + Al*Bh  (~fp32-accurate product of split operands)
__device__ __forceinline__ f32x4 mfma3(short8 ah, short8 al, short8 bh, short8 bl) {
    f32x4 acc = {0.f, 0.f, 0.f, 0.f};
    acc = __builtin_amdgcn_mfma_f32_16x16x32_bf16(al, bh, acc, 0, 0, 0);
    acc = __builtin_amdgcn_mfma_f32_16x16x32_bf16(ah, bl, acc, 0, 0, 0);
    acc = __builtin_amdgcn_mfma_f32_16x16x32_bf16(ah, bh, acc, 0, 0, 0);
    return acc;
}

// ---- init + dtype sniff (fresh every call) ----
__global__ __launch_bounds__(256) void k_init(const u16* __restrict__ atom16) {
    int i = blockIdx.x * 256 + threadIdx.x;
    if (i == 0) {
        int even_ok = 0;
        for (int j = 0; j < 1024; ++j) {
            float ve = bf2f(atom16[2 * j]);
            float ae = fabsf(ve);
            if (ve == 0.f || (ae > 9.3e-13f && ae < 1.1e12f)) even_ok++;
        }
        g_isf32 = (even_ok < 716) ? 1 : 0;
    }
    if (i < NNODES) {
        g_deg[i] = 0u;
        g_m[i] = 0x007FFFFFu;  // encf(-inf)
    }
    if (i < 40) g_stats[i] = 0.f;
}

// ---- weights -> split-bf16 transposed layouts + f32 biases ----
__global__ __launch_bounds__(256) void k_prep(
    const void* __restrict__ kw1, const void* __restrict__ kb1,
    const void* __restrict__ kw2, const void* __restrict__ kb2,
    const void* __restrict__ vw1, const void* __restrict__ vb1,
    const void* __restrict__ vw2, const void* __restrict__ vb2) {
    const int f32 = g_isf32;
    int t = blockIdx.x * 256 + threadIdx.x;
    if (t < 640 * 32) {               // W2T[n][k] = W2[k][n]
        int n = t >> 5, k = t & 31;
        split2(ldx(kw2, (size_t)k * 640 + n, f32), g_w2hk[t], g_w2lk[t]);
        split2(ldx(vw2, (size_t)k * 640 + n, f32), g_w2hv[t], g_w2lv[t]);
    }
    if (t < 1024) {                   // W1T[tt][s] = W1[s][tt]
        int tt = t >> 5, s = t & 31;
        split2(ldx(kw1, (size_t)s * 32 + tt, f32), g_w1hk[t], g_w1lk[t]);
        split2(ldx(vw1, (size_t)s * 32 + tt, f32), g_w1hv[t], g_w1lv[t]);
    }
    if (t < 640) { g_b2k[t] = ldx(kb2, t, f32); g_b2v[t] = ldx(vb2, t, f32); }
    if (t < 32)  { g_b1k[t] = ldx(kb1, t, f32); g_b1v[t] = ldx(vb1, t, f32); }
}

// ---- fused: q = irreps_linear(atom) per node + degree count ----
__global__ __launch_bounds__(256) void k_pre(
    const void* __restrict__ atom, const void* __restrict__ Wqs,
    const void* __restrict__ Wqv, const int* __restrict__ ei) {
    const int f32 = g_isf32;
    int idx = blockIdx.x * 256 + threadIdx.x;
    if (idx < NEDGES) atomicAdd(&g_deg[ei[NEDGES + idx]], 1u);
    int n = idx;
    if (n >= NNODES) return;
    const size_t ab = (size_t)n * 40;
    float qs[16];
    #pragma unroll
    for (int o = 0; o < 16; ++o) qs[o] = 0.f;
    #pragma unroll 1
    for (int i = 0; i < 16; ++i) {
        float ai = ldx(atom, ab + i, f32);
        #pragma unroll
        for (int o = 0; o < 16; ++o)
            qs[o] = fmaf(ai, ldx(Wqs, i * 16 + o, f32), qs[o]);
    }
    float qv[24];
    #pragma unroll
    for (int k = 0; k < 24; ++k) qv[k] = 0.f;
    #pragma unroll 1
    for (int i = 0; i < 8; ++i) {
        float a0 = ldx(atom, ab + 16 + 3*i + 0, f32);
        float a1 = ldx(atom, ab + 16 + 3*i + 1, f32);
        float a2 = ldx(atom, ab + 16 + 3*i + 2, f32);
        #pragma unroll
        for (int o = 0; o < 8; ++o) {
            float wv = ldx(Wqv, i * 8 + o, f32);
            qv[o*3+0] = fmaf(a0, wv, qv[o*3+0]);
            qv[o*3+1] = fmaf(a1, wv, qv[o*3+1]);
            qv[o*3+2] = fmaf(a2, wv, qv[o*3+2]);
        }
    }
    float* qp = g_q + (size_t)n * 40;
    #pragma unroll
    for (int o = 0; o < 16; ++o) qp[o] = qs[o];
    #pragma unroll
    for (int k = 0; k < 24; ++k) qp[16 + k] = qv[k];
}

__global__ __launch_bounds__(256) void k_scan() {
    __shared__ u32 part[256];
    int t = threadIdx.x;
    int lo = t * 40, hi = lo + 40; if (hi > NNODES) hi = NNODES; if (lo > NNODES) lo = NNODES;
    u32 s = 0;
    for (int i = lo; i < hi; ++i) s += g_deg[i];
    part[t] = s;
    __syncthreads();
    if (t == 0) {
        u32 run = 0;
        for (int i = 0; i < 256; ++i) { u32 v = part[i]; part[i] = run; run += v; }
    }
    __syncthreads();
    u32 run = part[t];
    for (int i = lo; i < hi; ++i) { g_off[i] = run; g_cur[i] = run; run += g_deg[i]; }
    if (t == 255) g_off[NNODES] = NEDGES;
}
__global__ __launch_bounds__(256) void k_fill(const int* __restrict__ ei) {
    int e = blockIdx.x * 256 + threadIdx.x;
    if (e < NEDGES) {
        u32 p = atomicAdd(&g_cur[ei[NEDGES + e]], 1u);
        g_csr[p] = e;
    }
}

// ========== fused edge kernel: barrier-free, wave-independent M-split ==========
// 64 edges/block, 4 waves; wave w owns edges [w*16, w*16+16) end-to-end.
#define A1S 40    // LDS row stride in shorts (80 B)
#define ACCS 41   // accbuf row stride in floats

__global__ __launch_bounds__(256, 3) void k_edge(
    const void* __restrict__ atom, const void* __restrict__ ef,
    const void* __restrict__ sh, const int* __restrict__ ei,
    void* __restrict__ out) {
    __shared__ __align__(16) float smF[91 * 64];       // TP factor table [row][edge]
    __shared__ __align__(16) u16   smA1h[64 * A1S];    // EF hi bf16 [edge][32]
    __shared__ __align__(16) u16   smA1l[64 * A1S];
    __shared__ __align__(16) u16   smA2h[64 * A1S];    // H hi bf16 [edge][32]
    __shared__ __align__(16) u16   smA2l[64 * A1S];
    __shared__ __align__(16) float smAcc[64 * ACCS];   // per-edge out rows [edge][40]

    const int f32 = g_isf32;
    const int t = threadIdx.x;
    const int w = t >> 6, lane = t & 63;
    const int quad = lane >> 4, c = lane & 15;
    const int eb = blockIdx.x * 64;

    // ---- folded passthrough copy of edge_features -> output part 1 ----
    if (f32) {
        const uint4* s = (const uint4*)ef;
        uint4* d = (uint4*)((char*)out + 1600000u);
        size_t i = (size_t)blockIdx.x * 512 + t;
        d[i] = s[i]; d[i + 256] = s[i + 256];
    } else {
        const uint4* s = (const uint4*)ef;
        uint4* d = (uint4*)((char*)out + 800000u);
        size_t i = (size_t)blockIdx.x * 256 + t;
        d[i] = s[i];
    }

    // ---- wave-local staging: lanes 0-15 x/factors, lanes 16-47 EF ----
    if (lane < 16) {
        const int e = w * 16 + lane;
        const int ge = eb + e;
        const int dst = ei[ge];
        float x[40];
        float ss, s0, s1, s2;
        if (f32) {
            const float4* xp = (const float4*)((const float*)atom + (size_t)dst * 40);
            #pragma unroll
            for (int i = 0; i < 10; ++i) {
                float4 v = xp[i];
                x[i*4+0] = v.x; x[i*4+1] = v.y; x[i*4+2] = v.z; x[i*4+3] = v.w;
            }
            float4 s4 = *(const float4*)((const float*)sh + (size_t)ge * 4);
            ss = s4.x; s0 = s4.y; s1 = s4.z; s2 = s4.w;
        } else {
            #pragma unroll
            for (int i = 0; i < 40; ++i) x[i] = bf2f(((const u16*)atom)[(size_t)dst * 40 + i]);
            ss = bf2f(((const u16*)sh)[(size_t)ge*4+0]);
            s0 = bf2f(((const u16*)sh)[(size_t)ge*4+1]);
            s1 = bf2f(((const u16*)sh)[(size_t)ge*4+2]);
            s2 = bf2f(((const u16*)sh)[(size_t)ge*4+3]);
        }
        #pragma unroll
        for (int i = 0; i < 16; ++i) {
            smF[i * 64 + e] = x[i] * ss;          // fb1 rows 0-15
            smF[(24 + i) * 64 + e] = x[i];        // fb3 rows 24-39
        }
        #pragma unroll
        for (int i = 0; i < 8; ++i) {
            float a0 = x[16+3*i], a1 = x[17+3*i], a2 = x[18+3*i];
            smF[(16 + i) * 64 + e] = C110 * (a0*s0 + a1*s1 + a2*s2);  // fb2 16-23
            smF[(40 + i) * 64 + e] = a0 * ss;                          // fb4 40-63
            smF[(48 + i) * 64 + e] = a1 * ss;
            smF[(56 + i) * 64 + e] = a2 * ss;
            smF[(64 + i) * 64 + e] = C111 * (a1*s2 - a2*s1);           // fb5 64-87
            smF[(72 + i) * 64 + e] = C111 * (a2*s0 - a0*s2);
            smF[(80 + i) * 64 + e] = C111 * (a0*s1 - a1*s0);
        }
        smF[88*64 + e] = s0; smF[89*64 + e] = s1; smF[90*64 + e] = s2;  // sv 88-90
    } else if (lane < 48) {
        const int el = (lane - 16) >> 1, half = (lane - 16) & 1;
        const int e = w * 16 + el;
        const int ge = eb + e;
        u32* dh = (u32*)(smA1h + e * A1S) + half * 8;
        u32* dl = (u32*)(smA1l + e * A1S) + half * 8;
        if (f32) {
            const float4* ep = (const float4*)((const float*)ef + (size_t)ge * 32 + half * 16);
            #pragma unroll
            for (int kq = 0; kq < 4; ++kq) {
                float4 v = ep[kq];
                u16 h0,l0,h1,l1,h2,l2,h3,l3;
                split2(v.x,h0,l0); split2(v.y,h1,l1); split2(v.z,h2,l2); split2(v.w,h3,l3);
                dh[kq*2+0] = (u32)h0 | ((u32)h1 << 16);
                dh[kq*2+1] = (u32)h2 | ((u32)h3 << 16);
                dl[kq*2+0] = (u32)l0 | ((u32)l1 << 16);
                dl[kq*2+1] = (u32)l2 | ((u32)l3 << 16);
            }
        } else {
            #pragma unroll
            for (int kk = 0; kk < 8; ++kk) {
                float v0 = bf2f(((const u16*)ef)[(size_t)ge*32 + half*16 + 2*kk]);
                float v1 = bf2f(((const u16*)ef)[(size_t)ge*32 + half*16 + 2*kk + 1]);
                u16 h0,l0,h1,l1;
                split2(v0,h0,l0); split2(v1,h1,l1);
                dh[kk] = (u32)h0 | ((u32)h1 << 16);
                dl[kk] = (u32)l0 | ((u32)l1 << 16);
            }
        }
    }
    // NO __syncthreads: all LDS rows are produced and consumed by the same wave.

    const int e0 = w * 16 + quad * 4;  // this lane's 4 edge-rows (local)
    const int o = c & 7, ch = c >> 3;
    const int el = lane >> 2, part = lane & 3;  // epilogue mapping

    #pragma unroll 1
    for (int p = 0; p < 2; ++p) {
        const u16* w1h = p ? g_w1hv : g_w1hk;
        const u16* w1l = p ? g_w1lv : g_w1lk;
        const u16* w2h = p ? g_w2hv : g_w2hk;
        const u16* w2l = p ? g_w2lv : g_w2lk;
        const float* b1 = p ? g_b1v : g_b1k;
        const float* b2 = p ? g_b2v : g_b2k;

        // ---- GEMM1: H = relu(EF @ W1 + b1) for own 16 edges ----
        {
            short8 ah = *(const short8*)(smA1h + (w*16 + c) * A1S + quad * 8);
            short8 al = *(const short8*)(smA1l + (w*16 + c) * A1S + quad * 8);
            #pragma unroll
            for (int nt = 0; nt < 2; ++nt) {
                short8 bh = *(const short8*)(w1h + (nt*16 + c) * 32 + quad * 8);
                short8 bl = *(const short8*)(w1l + (nt*16 + c) * 32 + quad * 8);
                f32x4 acc = mfma3(ah, al, bh, bl);
                float bias = b1[nt*16 + c];
                #pragma unroll
                for (int r = 0; r < 4; ++r) {
                    float hv = fmaxf(acc[r] + bias, 0.f);
                    u16 hh, hl;
                    split2(hv, hh, hl);
                    smA2h[(w*16 + quad*4 + r) * A1S + nt*16 + c] = hh;
                    smA2l[(w*16 + quad*4 + r) * A1S + nt*16 + c] = hl;
                }
            }
        }

        // ---- GEMM2 + fused TP over all 40 N-tiles for own 16 edges ----
        short8 afh = *(const short8*)(smA2h + (w*16 + c) * A1S + quad * 8);
        short8 afl = *(const short8*)(smA2l + (w*16 + c) * A1S + quad * 8);

        float aS[4] = {0.f,0.f,0.f,0.f};
        float aT[4] = {0.f,0.f,0.f,0.f};
        float aV[12] = {0.f,0.f,0.f,0.f,0.f,0.f,0.f,0.f,0.f,0.f,0.f,0.f};

        // blocks 1+2: tiles 0..23, f row = nt, out_s col = c
        #pragma unroll 4
        for (int nt = 0; nt < 24; ++nt) {
            short8 bh = *(const short8*)(w2h + (nt*16 + c) * 32 + quad * 8);
            short8 bl = *(const short8*)(w2l + (nt*16 + c) * 32 + quad * 8);
            float bb = b2[nt*16 + c];
            f32x4 C = mfma3(afh, afl, bh, bl);
            f32x4 f = *(const f32x4*)(smF + nt * 64 + e0);
            #pragma unroll
            for (int r = 0; r < 4; ++r) aS[r] = fmaf(C[r] + bb, f[r], aS[r]);
        }
        // block 3: tiles 24..31, i = 2*(nt-24)+ch, f row = 24+i -> t3 partial
        #pragma unroll 4
        for (int nt = 24; nt < 32; ++nt) {
            short8 bh = *(const short8*)(w2h + (nt*16 + c) * 32 + quad * 8);
            short8 bl = *(const short8*)(w2l + (nt*16 + c) * 32 + quad * 8);
            float bb = b2[nt*16 + c];
            f32x4 C = mfma3(afh, afl, bh, bl);
            f32x4 f = *(const f32x4*)(smF + (24 + 2*(nt-24) + ch) * 64 + e0);
            #pragma unroll
            for (int r = 0; r < 4; ++r) aT[r] = fmaf(C[r] + bb, f[r], aT[r]);
        }
        // block 4: tiles 32..35, f rows 40+d*8+i
        #pragma unroll 2
        for (int nt = 32; nt < 36; ++nt) {
            short8 bh = *(const short8*)(w2h + (nt*16 + c) * 32 + quad * 8);
            short8 bl = *(const short8*)(w2l + (nt*16 + c) * 32 + quad * 8);
            float bb = b2[nt*16 + c];
            f32x4 C = mfma3(afh, afl, bh, bl);
            const int i = 2*(nt-32) + ch;
            #pragma unroll
            for (int d = 0; d < 3; ++d) {
                f32x4 f = *(const f32x4*)(smF + (40 + d*8 + i) * 64 + e0);
                #pragma unroll
                for (int r = 0; r < 4; ++r) aV[d*4+r] = fmaf(C[r] + bb, f[r], aV[d*4+r]);
            }
        }
        // block 5: tiles 36..39, f rows 64+d*8+i
        #pragma unroll 2
        for (int nt = 36; nt < 40; ++nt) {
            short8 bh = *(const short8*)(w2h + (nt*16 + c) * 32 + quad * 8);
            short8 bl = *(const short8*)(w2l + (nt*16 + c) * 32 + quad * 8);
            float bb = b2[nt*16 + c];
            f32x4 C = mfma3(afh, afl, bh, bl);
            const int i = 2*(nt-36) + ch;
            #pragma unroll
            for (int d = 0; d < 3; ++d) {
                f32x4 f = *(const f32x4*)(smF + (64 + d*8 + i) * 64 + e0);
                #pragma unroll
                for (int r = 0; r < 4; ++r) aV[d*4+r] = fmaf(C[r] + bb, f[r], aV[d*4+r]);
            }
        }

        // ---- flush: out_s direct; out_v via intra-wave shuffle (c <-> c+8) ----
        #pragma unroll
        for (int r = 0; r < 4; ++r) smAcc[(e0 + r) * ACCS + c] = aS[r];
        #pragma unroll
        for (int r = 0; r < 4; ++r) aT[r] += __shfl_xor(aT[r], 8);
        #pragma unroll
        for (int d = 0; d < 3; ++d)
            #pragma unroll
            for (int r = 0; r < 4; ++r) aV[d*4+r] += __shfl_xor(aV[d*4+r], 8);
        if (ch == 0) {
            #pragma unroll
            for (int d = 0; d < 3; ++d) {
                f32x4 sv = *(const f32x4*)(smF + (88 + d) * 64 + e0);
                #pragma unroll
                for (int r = 0; r < 4; ++r)
                    smAcc[(e0 + r) * ACCS + 16 + o*3 + d] = aV[d*4+r] + aT[r] * sv[r];
            }
        }

        // ---- epilogue (wave-local, 4 lanes per edge) ----
        const int ge2 = eb + w * 16 + el;
        const float* ap = smAcc + (w * 16 + el) * ACCS + part * 10;
        if (p == 0) {
            const int src = ei[NEDGES + ge2];
            const float* qp = g_q + (size_t)src * 40 + part * 10;
            float partial = 0.f;
            #pragma unroll
            for (int d2 = 0; d2 < 10; ++d2) partial = fmaf(qp[d2], ap[d2], partial);
            partial += __shfl_xor(partial, 1);
            partial += __shfl_xor(partial, 2);
            if (part == 0) {
                g_attn[ge2] = partial;
                atomicMax(&g_m[src], encf(partial));
            }
        } else {
            float* vb = g_vbuf + (size_t)ge2 * 40 + part * 10;
            #pragma unroll
            for (int d2 = 0; d2 < 10; ++d2) vb[d2] = ap[d2];
        }
    }
}

// ---- per-node softmax gather (one wave per node; no global atomics) ----
__global__ __launch_bounds__(256) void k_gather() {
    int node = blockIdx.x * 4 + (threadIdx.x >> 6);
    int lane = threadIdx.x & 63;
    if (node >= NNODES) return;
    u32 s = g_off[node], epos = g_off[node + 1];
    float m = decf(g_m[node]);
    float den = 0.f, acc = 0.f;
    for (u32 p = s; p < epos; ++p) {
        int e = g_csr[p];
        float pex = expf(fminf(g_attn[e] - m, 0.f));
        den += pex;
        if (lane < 40) acc = fmaf(pex, g_vbuf[(size_t)e * 40 + lane], acc);
    }
    if (lane < 40) g_upd[node * 40 + lane] = acc;
    if (lane == 0) g_den[node] = den;
}

// ---- x = atom + upd/den ; batchnorm stats ----
__global__ __launch_bounds__(256) void k_stats(const void* __restrict__ atom) {
    const int f32 = g_isf32;
    int n = blockIdx.x * 256 + threadIdx.x;
    bool act = n < NNODES;
    float x[40];
    #pragma unroll
    for (int c = 0; c < 40; ++c) x[c] = 0.f;
    if (act) {
        float den = g_den[n];
        float inv = (den > 0.f) ? 1.f / den : 0.f;
        const float4* up = (const float4*)(g_upd + (size_t)n * 40);
        float4* xp = (float4*)(g_x + (size_t)n * 40);
        #pragma unroll 1
        for (int c = 0; c < 40; ++c) x[c] = ldx(atom, (size_t)n * 40 + c, f32);
        #pragma unroll
        for (int c = 0; c < 10; ++c) {
            float4 u = up[c];
            float4 r = make_float4(x[c*4+0] + u.x * inv, x[c*4+1] + u.y * inv,
                                   x[c*4+2] + u.z * inv, x[c*4+3] + u.w * inv);
            x[c*4+0] = r.x; x[c*4+1] = r.y; x[c*4+2] = r.z; x[c*4+3] = r.w;
            xp[c] = r;
        }
    }
    float st[40];
    #pragma unroll
    for (int c = 0; c < 16; ++c) st[c] = x[c];
    #pragma unroll
    for (int c = 0; c < 16; ++c) st[16 + c] = x[c] * x[c];
    #pragma unroll
    for (int i = 0; i < 8; ++i) {
        float a0 = x[16+3*i+0], a1 = x[16+3*i+1], a2 = x[16+3*i+2];
        st[32 + i] = a0*a0 + a1*a1 + a2*a2;
    }
    #pragma unroll
    for (int c = 0; c < 40; ++c) {
        float v = st[c];
        v += __shfl_xor(v, 1);  v += __shfl_xor(v, 2);  v += __shfl_xor(v, 4);
        v += __shfl_xor(v, 8);  v += __shfl_xor(v, 16); v += __shfl_xor(v, 32);
        st[c] = v;
    }
    if ((threadIdx.x & 63) == 0) {
        #pragma unroll
        for (int c = 0; c < 40; ++c) atomicAdd(g_stats + c, st[c]);
    }
}

__global__ void k_final(const void* __restrict__ bws, const void* __restrict__ bbs,
                        const void* __restrict__ bwv) {
    const int f32 = g_isf32;
    int t = threadIdx.x;
    const float invN = 1.f / (float)NNODES;
    if (t < 16) {
        float mu = g_stats[t] * invN;
        float var = fmaxf(g_stats[16 + t] * invN - mu * mu, 0.f);
        float isd = 1.f / sqrtf(var + 1e-5f);
        float sc = ldx(bws, t, f32) * isd;
        g_par[t] = sc;
        g_par[16 + t] = ldx(bbs, t, f32) - mu * sc;
    } else if (t >= 32 && t < 40) {
        int i = t - 32;
        float norm = g_stats[32 + i] * (invN / 3.f);
        g_par[32 + i] = ldx(bwv, i, f32) / sqrtf(norm + 1e-5f);
    }
}

__global__ __launch_bounds__(256) void k_out(void* __restrict__ out) {
    const int f32 = g_isf32;
    int n = blockIdx.x * 256 + threadIdx.x;
    if (n >= NNODES) return;
    const float* xp = g_x + (size_t)n * 40;
    float res[40];
    #pragma unroll
    for (int c = 0; c < 16; ++c) res[c] = xp[c] * g_par[c] + g_par[16 + c];
    #pragma unroll
    for (int i = 0; i < 8; ++i) {
        float s = g_par[32 + i];
        res[16+3*i+0] = xp[16+3*i+0] * s;
        res[16+3*i+1] = xp[16+3*i+1] * s;
        res[16+3*i+2] = xp[16+3*i+2] * s;
    }
    if (f32) {
        float* op = (float*)out + (size_t)n * 40;
        #pragma unroll
        for (int c = 0; c < 40; ++c) op[c] = res[c];
    } else {
        uint4* op = (uint4*)((u16*)out + (size_t)n * 40);
        #pragma unroll
        for (int c = 0; c < 5; ++c) {
            uint4 r;
            r.x = pack2(res[c*8+0], res[c*8+1]);
            r.y = pack2(res[c*8+2], res[c*8+3]);
            r.z = pack2(res[c*8+4], res[c*8+5]);
            r.w = pack2(res[c*8+6], res[c*8+7]);
            op[c] = r;
        }
    }
}

extern "C" void kernel_launch(void* const* d_in, const int* in_sizes, int n_in,
                              void* d_out, int out_size, void* d_ws, size_t ws_size,
                              hipStream_t stream) {
    const void* atom = d_in[0];
    const void* ef   = d_in[1];
    const void* sh   = d_in[2];
    const void* Wqs  = d_in[3];
    const void* Wqv  = d_in[4];
    const void* kw1  = d_in[5];
    const void* kb1  = d_in[6];
    const void* kw2  = d_in[7];
    const void* kb2  = d_in[8];
    const void* vw1  = d_in[9];
    const void* vb1  = d_in[10];
    const void* vw2  = d_in[11];
    const void* vb2  = d_in[12];
    const void* bws  = d_in[13];
    const void* bbs  = d_in[14];
    const void* bwv  = d_in[15];
    const int*  ei   = (const int*)d_in[16];

    k_init<<<40, 256, 0, stream>>>((const u16*)atom);
    k_prep<<<80, 256, 0, stream>>>(kw1, kb1, kw2, kb2, vw1, vb1, vw2, vb2);
    k_pre<<<625, 256, 0, stream>>>(atom, Wqs, Wqv, ei);
    k_scan<<<1, 256, 0, stream>>>();
    k_fill<<<625, 256, 0, stream>>>(ei);
    k_edge<<<2500, 256, 0, stream>>>(atom, ef, sh, ei, d_out);
    k_gather<<<2500, 256, 0, stream>>>();
    k_stats<<<40, 256, 0, stream>>>(atom);
    k_final<<<1, 64, 0, stream>>>(bws, bbs, bwv);
    k_out<<<40, 256, 0, stream>>>(d_out);
}

// Round 9
// 318.724 us; speedup vs baseline: 5.0354x; 1.3934x over previous
//
#include <hip/hip_runtime.h>
#include <hip/hip_bf16.h>

typedef unsigned short u16;
typedef unsigned int u32;
typedef _Float16 h16;

#define NNODES 10000
#define NEDGES 160000

#define C110 0.57735026918962576f
#define C111 0.70710678118654752f

typedef __attribute__((ext_vector_type(8))) _Float16 half8;
typedef __attribute__((ext_vector_type(4))) float f32x4;

// ---- module-owned scratch ----
__device__ int   g_isf32;
__device__ float g_q[NNODES * 40];
__device__ float g_x[NNODES * 40];
__device__ float g_attn[NEDGES];
__device__ u32   g_m[NNODES];
__device__ float g_stats[40];
__device__ float g_par[40];
__device__ float g_vbuf[(size_t)NEDGES * 40];
__device__ u32   g_deg[NNODES], g_cur[NNODES], g_off[NNODES + 1];
__device__ int   g_csr[NEDGES];
// weights: W1T split fp16 (hi+lo), W2T single fp16; biases f32
__device__ h16   g_w1hk[1024], g_w1lk[1024], g_w1hv[1024], g_w1lv[1024];
__device__ h16   g_w2k[640 * 32], g_w2v[640 * 32];
__device__ float g_b1k[32], g_b1v[32], g_b2k[640], g_b2v[640];

__device__ __forceinline__ float bf2f(u16 v) {
    return __uint_as_float(((u32)v) << 16);
}
__device__ __forceinline__ u32 f2bfbits(float f) {  // RNE
    u32 u = __float_as_uint(f);
    u32 r = 0x7FFFu + ((u >> 16) & 1u);
    return (u + r) >> 16;
}
__device__ __forceinline__ u32 pack2(float a, float b) {
    return f2bfbits(a) | (f2bfbits(b) << 16);
}
__device__ __forceinline__ u32 encf(float f) {
    u32 u = __float_as_uint(f);
    return (u & 0x80000000u) ? ~u : (u | 0x80000000u);
}
__device__ __forceinline__ float decf(u32 u) {
    return (u & 0x80000000u) ? __uint_as_float(u & 0x7FFFFFFFu) : __uint_as_float(~u);
}
__device__ __forceinline__ float ldx(const void* p, size_t i, int f32) {
    return f32 ? ((const float*)p)[i] : bf2f(((const u16*)p)[i]);
}
// split f32 -> fp16 hi + fp16 residual lo (~21-bit effective mantissa)
__device__ __forceinline__ void split2h(float v, h16& hi, h16& lo) {
    h16 h = (h16)v;
    hi = h;
    lo = (h16)(v - (float)h);
}

// ---- init + parallel dtype sniff (fresh every call) ----
__global__ __launch_bounds__(256) void k_init(const u16* __restrict__ atom16) {
    int i = blockIdx.x * 256 + threadIdx.x;
    if (blockIdx.x == 0 && threadIdx.x < 64) {
        int cnt = 0;
        #pragma unroll 4
        for (int j = threadIdx.x * 16; j < threadIdx.x * 16 + 16; ++j) {
            float ve = bf2f(atom16[2 * j]);
            float ae = fabsf(ve);
            if (ve == 0.f || (ae > 9.3e-13f && ae < 1.1e12f)) cnt++;
        }
        cnt += __shfl_xor(cnt, 1);  cnt += __shfl_xor(cnt, 2);
        cnt += __shfl_xor(cnt, 4);  cnt += __shfl_xor(cnt, 8);
        cnt += __shfl_xor(cnt, 16); cnt += __shfl_xor(cnt, 32);
        if (threadIdx.x == 0) g_isf32 = (cnt < 716) ? 1 : 0;
    }
    if (i < NNODES) {
        g_deg[i] = 0u;
        g_m[i] = 0x007FFFFFu;  // encf(-inf)
    }
    if (i < 40) g_stats[i] = 0.f;
}

// ---- weights -> fp16 tables (W1 split, W2 single) + f32 biases ----
__global__ __launch_bounds__(256) void k_prep(
    const void* __restrict__ kw1, const void* __restrict__ kb1,
    const void* __restrict__ kw2, const void* __restrict__ kb2,
    const void* __restrict__ vw1, const void* __restrict__ vb1,
    const void* __restrict__ vw2, const void* __restrict__ vb2) {
    const int f32 = g_isf32;
    int t = blockIdx.x * 256 + threadIdx.x;
    if (t < 640 * 32) {               // W2T[n][k] = W2[k][n]
        int n = t >> 5, k = t & 31;
        g_w2k[t] = (h16)ldx(kw2, (size_t)k * 640 + n, f32);
        g_w2v[t] = (h16)ldx(vw2, (size_t)k * 640 + n, f32);
    }
    if (t < 1024) {                   // W1T[tt][s] = W1[s][tt]
        int tt = t >> 5, s = t & 31;
        split2h(ldx(kw1, (size_t)s * 32 + tt, f32), g_w1hk[t], g_w1lk[t]);
        split2h(ldx(vw1, (size_t)s * 32 + tt, f32), g_w1hv[t], g_w1lv[t]);
    }
    if (t < 640) { g_b2k[t] = ldx(kb2, t, f32); g_b2v[t] = ldx(vb2, t, f32); }
    if (t < 32)  { g_b1k[t] = ldx(kb1, t, f32); g_b1v[t] = ldx(vb1, t, f32); }
}

// ---- fused: q = irreps_linear(atom) per node + degree count ----
__global__ __launch_bounds__(256) void k_pre(
    const void* __restrict__ atom, const void* __restrict__ Wqs,
    const void* __restrict__ Wqv, const int* __restrict__ ei) {
    const int f32 = g_isf32;
    int idx = blockIdx.x * 256 + threadIdx.x;
    if (idx < NEDGES) atomicAdd(&g_deg[ei[NEDGES + idx]], 1u);
    int n = idx;
    if (n >= NNODES) return;
    float x[40];
    if (f32) {
        const float4* ap = (const float4*)((const float*)atom + (size_t)n * 40);
        #pragma unroll
        for (int c = 0; c < 10; ++c) {
            float4 v = ap[c];
            x[c*4+0] = v.x; x[c*4+1] = v.y; x[c*4+2] = v.z; x[c*4+3] = v.w;
        }
    } else {
        #pragma unroll 1
        for (int c = 0; c < 40; ++c) x[c] = bf2f(((const u16*)atom)[(size_t)n * 40 + c]);
    }
    float qs[16];
    #pragma unroll
    for (int o = 0; o < 16; ++o) qs[o] = 0.f;
    #pragma unroll 1
    for (int i = 0; i < 16; ++i) {
        float ai = x[i];
        #pragma unroll
        for (int o = 0; o < 16; ++o)
            qs[o] = fmaf(ai, ldx(Wqs, i * 16 + o, f32), qs[o]);
    }
    float qv[24];
    #pragma unroll
    for (int k = 0; k < 24; ++k) qv[k] = 0.f;
    #pragma unroll 1
    for (int i = 0; i < 8; ++i) {
        float a0 = x[16 + 3*i + 0], a1 = x[16 + 3*i + 1], a2 = x[16 + 3*i + 2];
        #pragma unroll
        for (int o = 0; o < 8; ++o) {
            float wv = ldx(Wqv, i * 8 + o, f32);
            qv[o*3+0] = fmaf(a0, wv, qv[o*3+0]);
            qv[o*3+1] = fmaf(a1, wv, qv[o*3+1]);
            qv[o*3+2] = fmaf(a2, wv, qv[o*3+2]);
        }
    }
    float* qp = g_q + (size_t)n * 40;
    #pragma unroll
    for (int o = 0; o < 16; ++o) qp[o] = qs[o];
    #pragma unroll
    for (int k = 0; k < 24; ++k) qp[16 + k] = qv[k];
}

// ---- parallel exclusive scan of degrees -> CSR offsets ----
__global__ __launch_bounds__(256) void k_scan() {
    __shared__ u32 part[256];
    int t = threadIdx.x;
    int lo = t * 40, hi = lo + 40; if (hi > NNODES) hi = NNODES; if (lo > NNODES) lo = NNODES;
    u32 s = 0;
    for (int i = lo; i < hi; ++i) s += g_deg[i];
    part[t] = s;
    __syncthreads();
    #pragma unroll
    for (int d = 1; d < 256; d <<= 1) {
        u32 v = (t >= d) ? part[t - d] : 0u;
        __syncthreads();
        part[t] += v;
        __syncthreads();
    }
    u32 run = part[t] - s;   // exclusive
    for (int i = lo; i < hi; ++i) { g_off[i] = run; g_cur[i] = run; run += g_deg[i]; }
    if (t == 255) g_off[NNODES] = NEDGES;
}
__global__ __launch_bounds__(256) void k_fill(const int* __restrict__ ei) {
    int e = blockIdx.x * 256 + threadIdx.x;
    if (e < NEDGES) {
        u32 p = atomicAdd(&g_cur[ei[NEDGES + e]], 1u);
        g_csr[p] = e;
    }
}

// ========== fused edge kernel: barrier-free, wave-independent M-split ==========
// 64 edges/block, 4 waves; wave w owns edges [w*16, w*16+16) end-to-end.
// GEMM1: split-fp16 x split-fp16 (3 MFMA). GEMM2: split-A x single-fp16-B (2 MFMA).
#define A1S 40    // LDS row stride in halves (80 B)
#define ACCS 41   // accbuf row stride in floats

__global__ __launch_bounds__(256, 3) void k_edge(
    const void* __restrict__ atom, const void* __restrict__ ef,
    const void* __restrict__ sh, const int* __restrict__ ei,
    void* __restrict__ out) {
    __shared__ __align__(16) float smF[91 * 64];       // TP factor table [row][edge]
    __shared__ __align__(16) h16   smA1h[64 * A1S];    // EF hi fp16 [edge][32]
    __shared__ __align__(16) h16   smA1l[64 * A1S];
    __shared__ __align__(16) h16   smA2h[64 * A1S];    // H hi fp16 [edge][32]
    __shared__ __align__(16) h16   smA2l[64 * A1S];
    __shared__ __align__(16) float smAcc[64 * ACCS];   // per-edge out rows [edge][40]

    const int f32 = g_isf32;
    const int t = threadIdx.x;
    const int w = t >> 6, lane = t & 63;
    const int quad = lane >> 4, c = lane & 15;
    const int eb = blockIdx.x * 64;

    // ---- folded passthrough copy of edge_features -> output part 1 ----
    if (f32) {
        const uint4* s = (const uint4*)ef;
        uint4* d = (uint4*)((char*)out + 1600000u);
        size_t i = (size_t)blockIdx.x * 512 + t;
        d[i] = s[i]; d[i + 256] = s[i + 256];
    } else {
        const uint4* s = (const uint4*)ef;
        uint4* d = (uint4*)((char*)out + 800000u);
        size_t i = (size_t)blockIdx.x * 256 + t;
        d[i] = s[i];
    }

    // ---- wave-local staging: lanes 0-15 x/factors, lanes 16-47 EF ----
    if (lane < 16) {
        const int e = w * 16 + lane;
        const int ge = eb + e;
        const int dst = ei[ge];
        float x[40];
        float ss, s0, s1, s2;
        if (f32) {
            const float4* xp = (const float4*)((const float*)atom + (size_t)dst * 40);
            #pragma unroll
            for (int i = 0; i < 10; ++i) {
                float4 v = xp[i];
                x[i*4+0] = v.x; x[i*4+1] = v.y; x[i*4+2] = v.z; x[i*4+3] = v.w;
            }
            float4 s4 = *(const float4*)((const float*)sh + (size_t)ge * 4);
            ss = s4.x; s0 = s4.y; s1 = s4.z; s2 = s4.w;
        } else {
            #pragma unroll
            for (int i = 0; i < 40; ++i) x[i] = bf2f(((const u16*)atom)[(size_t)dst * 40 + i]);
            ss = bf2f(((const u16*)sh)[(size_t)ge*4+0]);
            s0 = bf2f(((const u16*)sh)[(size_t)ge*4+1]);
            s1 = bf2f(((const u16*)sh)[(size_t)ge*4+2]);
            s2 = bf2f(((const u16*)sh)[(size_t)ge*4+3]);
        }
        #pragma unroll
        for (int i = 0; i < 16; ++i) {
            smF[i * 64 + e] = x[i] * ss;          // fb1 rows 0-15
            smF[(24 + i) * 64 + e] = x[i];        // fb3 rows 24-39
        }
        #pragma unroll
        for (int i = 0; i < 8; ++i) {
            float a0 = x[16+3*i], a1 = x[17+3*i], a2 = x[18+3*i];
            smF[(16 + i) * 64 + e] = C110 * (a0*s0 + a1*s1 + a2*s2);  // fb2 16-23
            smF[(40 + i) * 64 + e] = a0 * ss;                          // fb4 40-63
            smF[(48 + i) * 64 + e] = a1 * ss;
            smF[(56 + i) * 64 + e] = a2 * ss;
            smF[(64 + i) * 64 + e] = C111 * (a1*s2 - a2*s1);           // fb5 64-87
            smF[(72 + i) * 64 + e] = C111 * (a2*s0 - a0*s2);
            smF[(80 + i) * 64 + e] = C111 * (a0*s1 - a1*s0);
        }
        smF[88*64 + e] = s0; smF[89*64 + e] = s1; smF[90*64 + e] = s2;  // sv 88-90
    } else if (lane < 48) {
        const int el = (lane - 16) >> 1, half = (lane - 16) & 1;
        const int e = w * 16 + el;
        const int ge = eb + e;
        h16* dh = smA1h + e * A1S + half * 16;
        h16* dl = smA1l + e * A1S + half * 16;
        if (f32) {
            const float4* ep = (const float4*)((const float*)ef + (size_t)ge * 32 + half * 16);
            #pragma unroll
            for (int kq = 0; kq < 4; ++kq) {
                float4 v = ep[kq];
                split2h(v.x, dh[kq*4+0], dl[kq*4+0]);
                split2h(v.y, dh[kq*4+1], dl[kq*4+1]);
                split2h(v.z, dh[kq*4+2], dl[kq*4+2]);
                split2h(v.w, dh[kq*4+3], dl[kq*4+3]);
            }
        } else {
            #pragma unroll
            for (int kk = 0; kk < 16; ++kk) {
                float v0 = bf2f(((const u16*)ef)[(size_t)ge*32 + half*16 + kk]);
                split2h(v0, dh[kk], dl[kk]);
            }
        }
    }
    // NO __syncthreads: all LDS rows are produced and consumed by the same wave.

    const int e0 = w * 16 + quad * 4;  // this lane's 4 edge-rows (local)
    const int o = c & 7, ch = c >> 3;
    const int el = lane >> 2, part = lane & 3;  // epilogue mapping

    #pragma unroll 1
    for (int p = 0; p < 2; ++p) {
        const h16* w1h = p ? g_w1hv : g_w1hk;
        const h16* w1l = p ? g_w1lv : g_w1lk;
        const h16* w2  = p ? g_w2v  : g_w2k;
        const float* b1 = p ? g_b1v : g_b1k;
        const float* b2 = p ? g_b2v : g_b2k;

        // ---- GEMM1: H = relu(EF @ W1 + b1), ~fp32-exact (3 MFMA) ----
        {
            half8 ah = *(const half8*)(smA1h + (w*16 + c) * A1S + quad * 8);
            half8 al = *(const half8*)(smA1l + (w*16 + c) * A1S + quad * 8);
            #pragma unroll
            for (int nt = 0; nt < 2; ++nt) {
                half8 bh = *(const half8*)(w1h + (nt*16 + c) * 32 + quad * 8);
                half8 bl = *(const half8*)(w1l + (nt*16 + c) * 32 + quad * 8);
                f32x4 acc = {0.f, 0.f, 0.f, 0.f};
                acc = __builtin_amdgcn_mfma_f32_16x16x32_f16(al, bh, acc, 0, 0, 0);
                acc = __builtin_amdgcn_mfma_f32_16x16x32_f16(ah, bl, acc, 0, 0, 0);
                acc = __builtin_amdgcn_mfma_f32_16x16x32_f16(ah, bh, acc, 0, 0, 0);
                float bias = b1[nt*16 + c];
                #pragma unroll
                for (int r = 0; r < 4; ++r) {
                    float hv = fmaxf(acc[r] + bias, 0.f);
                    split2h(hv, smA2h[(w*16 + quad*4 + r) * A1S + nt*16 + c],
                                smA2l[(w*16 + quad*4 + r) * A1S + nt*16 + c]);
                }
            }
        }

        // ---- GEMM2 + fused TP: split-A x single-B (2 MFMA/tile) ----
        half8 afh = *(const half8*)(smA2h + (w*16 + c) * A1S + quad * 8);
        half8 afl = *(const half8*)(smA2l + (w*16 + c) * A1S + quad * 8);

        float aS[4] = {0.f,0.f,0.f,0.f};
        float aT[4] = {0.f,0.f,0.f,0.f};
        float aV[12] = {0.f,0.f,0.f,0.f,0.f,0.f,0.f,0.f,0.f,0.f,0.f,0.f};

        // blocks 1+2: tiles 0..23, f row = nt, out_s col = c
        #pragma unroll 4
        for (int nt = 0; nt < 24; ++nt) {
            half8 b = *(const half8*)(w2 + (nt*16 + c) * 32 + quad * 8);
            float bb = b2[nt*16 + c];
            f32x4 C = {0.f,0.f,0.f,0.f};
            C = __builtin_amdgcn_mfma_f32_16x16x32_f16(afl, b, C, 0, 0, 0);
            C = __builtin_amdgcn_mfma_f32_16x16x32_f16(afh, b, C, 0, 0, 0);
            f32x4 f = *(const f32x4*)(smF + nt * 64 + e0);
            #pragma unroll
            for (int r = 0; r < 4; ++r) aS[r] = fmaf(C[r] + bb, f[r], aS[r]);
        }
        // block 3: tiles 24..31, i = 2*(nt-24)+ch, f row = 24+i -> t3 partial
        #pragma unroll 4
        for (int nt = 24; nt < 32; ++nt) {
            half8 b = *(const half8*)(w2 + (nt*16 + c) * 32 + quad * 8);
            float bb = b2[nt*16 + c];
            f32x4 C = {0.f,0.f,0.f,0.f};
            C = __builtin_amdgcn_mfma_f32_16x16x32_f16(afl, b, C, 0, 0, 0);
            C = __builtin_amdgcn_mfma_f32_16x16x32_f16(afh, b, C, 0, 0, 0);
            f32x4 f = *(const f32x4*)(smF + (24 + 2*(nt-24) + ch) * 64 + e0);
            #pragma unroll
            for (int r = 0; r < 4; ++r) aT[r] = fmaf(C[r] + bb, f[r], aT[r]);
        }
        // block 4: tiles 32..35, f rows 40+d*8+i
        #pragma unroll 2
        for (int nt = 32; nt < 36; ++nt) {
            half8 b = *(const half8*)(w2 + (nt*16 + c) * 32 + quad * 8);
            float bb = b2[nt*16 + c];
            f32x4 C = {0.f,0.f,0.f,0.f};
            C = __builtin_amdgcn_mfma_f32_16x16x32_f16(afl, b, C, 0, 0, 0);
            C = __builtin_amdgcn_mfma_f32_16x16x32_f16(afh, b, C, 0, 0, 0);
            const int i = 2*(nt-32) + ch;
            #pragma unroll
            for (int d = 0; d < 3; ++d) {
                f32x4 f = *(const f32x4*)(smF + (40 + d*8 + i) * 64 + e0);
                #pragma unroll
                for (int r = 0; r < 4; ++r) aV[d*4+r] = fmaf(C[r] + bb, f[r], aV[d*4+r]);
            }
        }
        // block 5: tiles 36..39, f rows 64+d*8+i
        #pragma unroll 2
        for (int nt = 36; nt < 40; ++nt) {
            half8 b = *(const half8*)(w2 + (nt*16 + c) * 32 + quad * 8);
            float bb = b2[nt*16 + c];
            f32x4 C = {0.f,0.f,0.f,0.f};
            C = __builtin_amdgcn_mfma_f32_16x16x32_f16(afl, b, C, 0, 0, 0);
            C = __builtin_amdgcn_mfma_f32_16x16x32_f16(afh, b, C, 0, 0, 0);
            const int i = 2*(nt-36) + ch;
            #pragma unroll
            for (int d = 0; d < 3; ++d) {
                f32x4 f = *(const f32x4*)(smF + (64 + d*8 + i) * 64 + e0);
                #pragma unroll
                for (int r = 0; r < 4; ++r) aV[d*4+r] = fmaf(C[r] + bb, f[r], aV[d*4+r]);
            }
        }

        // ---- flush: out_s direct; out_v via intra-wave shuffle (c <-> c+8) ----
        #pragma unroll
        for (int r = 0; r < 4; ++r) smAcc[(e0 + r) * ACCS + c] = aS[r];
        #pragma unroll
        for (int r = 0; r < 4; ++r) aT[r] += __shfl_xor(aT[r], 8);
        #pragma unroll
        for (int d = 0; d < 3; ++d)
            #pragma unroll
            for (int r = 0; r < 4; ++r) aV[d*4+r] += __shfl_xor(aV[d*4+r], 8);
        if (ch == 0) {
            #pragma unroll
            for (int d = 0; d < 3; ++d) {
                f32x4 sv = *(const f32x4*)(smF + (88 + d) * 64 + e0);
                #pragma unroll
                for (int r = 0; r < 4; ++r)
                    smAcc[(e0 + r) * ACCS + 16 + o*3 + d] = aV[d*4+r] + aT[r] * sv[r];
            }
        }

        // ---- epilogue (wave-local, 4 lanes per edge) ----
        const int ge2 = eb + w * 16 + el;
        const float* ap = smAcc + (w * 16 + el) * ACCS + part * 10;
        if (p == 0) {
            const int src = ei[NEDGES + ge2];
            const float* qp = g_q + (size_t)src * 40 + part * 10;
            float partial = 0.f;
            #pragma unroll
            for (int d2 = 0; d2 < 10; ++d2) partial = fmaf(qp[d2], ap[d2], partial);
            partial += __shfl_xor(partial, 1);
            partial += __shfl_xor(partial, 2);
            if (part == 0) {
                g_attn[ge2] = partial;
                atomicMax(&g_m[src], encf(partial));
            }
        } else {
            float* vb = g_vbuf + (size_t)ge2 * 40 + part * 10;
            #pragma unroll
            for (int d2 = 0; d2 < 10; ++d2) vb[d2] = ap[d2];
        }
    }
}

// ---- fused: per-node softmax gather + x = atom + upd/den + batchnorm stats ----
__global__ __launch_bounds__(256) void k_post(const void* __restrict__ atom) {
    __shared__ float part[40];
    const int f32 = g_isf32;
    const int node = blockIdx.x * 4 + (threadIdx.x >> 6);   // 2500*4 == NNODES exactly
    const int lane = threadIdx.x & 63;
    if (threadIdx.x < 40) part[threadIdx.x] = 0.f;
    __syncthreads();

    u32 s = g_off[node], epos = g_off[node + 1];
    float m = decf(g_m[node]);
    float den = 0.f, acc = 0.f;
    for (u32 p = s; p < epos; ++p) {
        int e = g_csr[p];
        float pex = expf(fminf(g_attn[e] - m, 0.f));
        den += pex;   // pex is lane-invariant: every lane holds the full denominator
        if (lane < 40) acc = fmaf(pex, g_vbuf[(size_t)e * 40 + lane], acc);
    }
    float inv = (den > 0.f) ? 1.f / den : 0.f;
    float xv = 0.f;
    if (lane < 40) {
        xv = ldx(atom, (size_t)node * 40 + lane, f32) + acc * inv;
        g_x[(size_t)node * 40 + lane] = xv;
    }
    // stats: lanes 0-15 scalar sums; vector norms from lane triplets
    if (lane < 16) {
        atomicAdd(&part[lane], xv);
        atomicAdd(&part[16 + lane], xv * xv);
    }
    float sq = xv * xv;
    float tri = sq + __shfl_down(sq, 1) + __shfl_down(sq, 2);
    if (lane >= 16 && lane < 40 && ((lane - 16) % 3 == 0))
        atomicAdd(&part[32 + (lane - 16) / 3], tri);
    __syncthreads();
    if (threadIdx.x < 40) atomicAdd(&g_stats[threadIdx.x], part[threadIdx.x]);
}

__global__ void k_final(const void* __restrict__ bws, const void* __restrict__ bbs,
                        const void* __restrict__ bwv) {
    const int f32 = g_isf32;
    int t = threadIdx.x;
    const float invN = 1.f / (float)NNODES;
    if (t < 16) {
        float mu = g_stats[t] * invN;
        float var = fmaxf(g_stats[16 + t] * invN - mu * mu, 0.f);
        float isd = 1.f / sqrtf(var + 1e-5f);
        float sc = ldx(bws, t, f32) * isd;
        g_par[t] = sc;
        g_par[16 + t] = ldx(bbs, t, f32) - mu * sc;
    } else if (t >= 32 && t < 40) {
        int i = t - 32;
        float norm = g_stats[32 + i] * (invN / 3.f);
        g_par[32 + i] = ldx(bwv, i, f32) / sqrtf(norm + 1e-5f);
    }
}

__global__ __launch_bounds__(256) void k_out(void* __restrict__ out) {
    const int f32 = g_isf32;
    int n = blockIdx.x * 256 + threadIdx.x;
    if (n >= NNODES) return;
    const float4* xp4 = (const float4*)(g_x + (size_t)n * 40);
    float xp[40];
    #pragma unroll
    for (int c = 0; c < 10; ++c) {
        float4 v = xp4[c];
        xp[c*4+0] = v.x; xp[c*4+1] = v.y; xp[c*4+2] = v.z; xp[c*4+3] = v.w;
    }
    float res[40];
    #pragma unroll
    for (int c = 0; c < 16; ++c) res[c] = xp[c] * g_par[c] + g_par[16 + c];
    #pragma unroll
    for (int i = 0; i < 8; ++i) {
        float s = g_par[32 + i];
        res[16+3*i+0] = xp[16+3*i+0] * s;
        res[16+3*i+1] = xp[16+3*i+1] * s;
        res[16+3*i+2] = xp[16+3*i+2] * s;
    }
    if (f32) {
        float4* op = (float4*)((float*)out + (size_t)n * 40);
        #pragma unroll
        for (int c = 0; c < 10; ++c)
            op[c] = make_float4(res[c*4+0], res[c*4+1], res[c*4+2], res[c*4+3]);
    } else {
        uint4* op = (uint4*)((u16*)out + (size_t)n * 40);
        #pragma unroll
        for (int c = 0; c < 5; ++c) {
            uint4 r;
            r.x = pack2(res[c*8+0], res[c*8+1]);
            r.y = pack2(res[c*8+2], res[c*8+3]);
            r.z = pack2(res[c*8+4], res[c*8+5]);
            r.w = pack2(res[c*8+6], res[c*8+7]);
            op[c] = r;
        }
    }
}

extern "C" void kernel_launch(void* const* d_in, const int* in_sizes, int n_in,
                              void* d_out, int out_size, void* d_ws, size_t ws_size,
                              hipStream_t stream) {
    const void* atom = d_in[0];
    const void* ef   = d_in[1];
    const void* sh   = d_in[2];
    const void* Wqs  = d_in[3];
    const void* Wqv  = d_in[4];
    const void* kw1  = d_in[5];
    const void* kb1  = d_in[6];
    const void* kw2  = d_in[7];
    const void* kb2  = d_in[8];
    const void* vw1  = d_in[9];
    const void* vb1  = d_in[10];
    const void* vw2  = d_in[11];
    const void* vb2  = d_in[12];
    const void* bws  = d_in[13];
    const void* bbs  = d_in[14];
    const void* bwv  = d_in[15];
    const int*  ei   = (const int*)d_in[16];

    k_init<<<40, 256, 0, stream>>>((const u16*)atom);
    k_prep<<<80, 256, 0, stream>>>(kw1, kb1, kw2, kb2, vw1, vb1, vw2, vb2);
    k_pre<<<625, 256, 0, stream>>>(atom, Wqs, Wqv, ei);
    k_scan<<<1, 256, 0, stream>>>();
    k_fill<<<625, 256, 0, stream>>>(ei);
    k_edge<<<2500, 256, 0, stream>>>(atom, ef, sh, ei, d_out);
    k_post<<<2500, 256, 0, stream>>>(atom);
    k_final<<<1, 64, 0, stream>>>(bws, bbs, bwv);
    k_out<<<40, 256, 0, stream>>>(d_out);
}

// Round 11
// 294.043 us; speedup vs baseline: 5.4581x; 1.0839x over previous
//
#include <hip/hip_runtime.h>
#include <hip/hip_bf16.h>

typedef unsigned short u16;
typedef unsigned int u32;
typedef _Float16 h16;

#define NNODES 10000
#define NEDGES 160000

#define C110 0.57735026918962576f
#define C111 0.70710678118654752f

typedef __attribute__((ext_vector_type(8))) _Float16 half8;
typedef __attribute__((ext_vector_type(4))) float f32x4;

// ---- module-owned scratch ----
__device__ int   g_isf32;
__device__ float g_q[NNODES * 40];
__device__ float g_x[NNODES * 40];
__device__ float g_attn[NEDGES];
__device__ float g_stats[40];
__device__ float g_par[40];
__device__ float g_vbuf[(size_t)NEDGES * 40];
// 8-way privatized (XCD-heuristic) softmax-max + bucket CSR
__device__ u32   g_m8[8 * NNODES];
__device__ u32   g_cnt8[8 * NNODES];
__device__ int   g_bucket[(size_t)NNODES * 128];   // [node][slice*16+slot]
// weights: W1T split fp16 (hi+lo), W2T single fp16; biases f32
__device__ h16   g_w1hk[1024], g_w1lk[1024], g_w1hv[1024], g_w1lv[1024];
__device__ h16   g_w2k[640 * 32], g_w2v[640 * 32];
__device__ float g_b1k[32], g_b1v[32], g_b2k[640], g_b2v[640];

__device__ __forceinline__ float bf2f(u16 v) {
    return __uint_as_float(((u32)v) << 16);
}
__device__ __forceinline__ u32 f2bfbits(float f) {  // RNE
    u32 u = __float_as_uint(f);
    u32 r = 0x7FFFu + ((u >> 16) & 1u);
    return (u + r) >> 16;
}
__device__ __forceinline__ u32 pack2(float a, float b) {
    return f2bfbits(a) | (f2bfbits(b) << 16);
}
__device__ __forceinline__ u32 encf(float f) {
    u32 u = __float_as_uint(f);
    return (u & 0x80000000u) ? ~u : (u | 0x80000000u);
}
__device__ __forceinline__ float decf(u32 u) {
    return (u & 0x80000000u) ? __uint_as_float(u & 0x7FFFFFFFu) : __uint_as_float(~u);
}
__device__ __forceinline__ float ldx(const void* p, size_t i, int f32) {
    return f32 ? ((const float*)p)[i] : bf2f(((const u16*)p)[i]);
}
// split f32 -> fp16 hi + fp16 residual lo (~21-bit effective mantissa)
__device__ __forceinline__ void split2h(float v, h16& hi, h16& lo) {
    h16 h = (h16)v;
    hi = h;
    lo = (h16)(v - (float)h);
}

// ---- init + parallel dtype sniff (fresh every call) ----
__global__ __launch_bounds__(256) void k_init(const u16* __restrict__ atom16) {
    int i = blockIdx.x * 256 + threadIdx.x;
    if (blockIdx.x == 0 && threadIdx.x < 64) {
        int cnt = 0;
        #pragma unroll 4
        for (int j = threadIdx.x * 16; j < threadIdx.x * 16 + 16; ++j) {
            float ve = bf2f(atom16[2 * j]);
            float ae = fabsf(ve);
            if (ve == 0.f || (ae > 9.3e-13f && ae < 1.1e12f)) cnt++;
        }
        cnt += __shfl_xor(cnt, 1);  cnt += __shfl_xor(cnt, 2);
        cnt += __shfl_xor(cnt, 4);  cnt += __shfl_xor(cnt, 8);
        cnt += __shfl_xor(cnt, 16); cnt += __shfl_xor(cnt, 32);
        if (threadIdx.x == 0) g_isf32 = (cnt < 716) ? 1 : 0;
    }
    if (i < 8 * NNODES) {
        g_cnt8[i] = 0u;
        g_m8[i] = 0x007FFFFFu;  // encf(-inf)
    }
    if (i < 40) g_stats[i] = 0.f;
}

// ---- weights -> fp16 tables (coalesced reads, strided writes) ----
__global__ __launch_bounds__(256) void k_prep(
    const void* __restrict__ kw1, const void* __restrict__ kb1,
    const void* __restrict__ kw2, const void* __restrict__ kb2,
    const void* __restrict__ vw1, const void* __restrict__ vb1,
    const void* __restrict__ vw2, const void* __restrict__ vb2) {
    const int f32 = g_isf32;
    int t = blockIdx.x * 256 + threadIdx.x;
    if (t < 640 * 32) {               // t = k*640 + n (coalesced read of W2)
        int k = t / 640, n = t - k * 640;
        g_w2k[n * 32 + k] = (h16)ldx(kw2, t, f32);
        g_w2v[n * 32 + k] = (h16)ldx(vw2, t, f32);
    }
    if (t < 1024) {                   // t = s*32 + tt (coalesced read of W1)
        int s = t >> 5, tt = t & 31;
        split2h(ldx(kw1, t, f32), g_w1hk[tt * 32 + s], g_w1lk[tt * 32 + s]);
        split2h(ldx(vw1, t, f32), g_w1hv[tt * 32 + s], g_w1lv[tt * 32 + s]);
    }
    if (t < 640) { g_b2k[t] = ldx(kb2, t, f32); g_b2v[t] = ldx(vb2, t, f32); }
    if (t < 32)  { g_b1k[t] = ldx(kb1, t, f32); g_b1v[t] = ldx(vb1, t, f32); }
}

// ---- q = irreps_linear(atom), Wq staged in LDS ----
__global__ __launch_bounds__(256) void k_q(
    const void* __restrict__ atom, const void* __restrict__ Wqs,
    const void* __restrict__ Wqv) {
    __shared__ float sW[320];   // 256 Wqs + 64 Wqv
    const int f32 = g_isf32;
    int n = blockIdx.x * 256 + threadIdx.x;
    if (threadIdx.x < 256) sW[threadIdx.x] = ldx(Wqs, threadIdx.x, f32);
    if (threadIdx.x < 64)  sW[256 + threadIdx.x] = ldx(Wqv, threadIdx.x, f32);
    __syncthreads();
    if (n >= NNODES) return;
    float x[40];
    if (f32) {
        const float4* ap = (const float4*)((const float*)atom + (size_t)n * 40);
        #pragma unroll
        for (int c = 0; c < 10; ++c) {
            float4 v = ap[c];
            x[c*4+0] = v.x; x[c*4+1] = v.y; x[c*4+2] = v.z; x[c*4+3] = v.w;
        }
    } else {
        #pragma unroll 1
        for (int c = 0; c < 40; ++c) x[c] = bf2f(((const u16*)atom)[(size_t)n * 40 + c]);
    }
    float qs[16];
    #pragma unroll
    for (int o = 0; o < 16; ++o) qs[o] = 0.f;
    #pragma unroll 1
    for (int i = 0; i < 16; ++i) {
        float ai = x[i];
        #pragma unroll
        for (int o = 0; o < 16; ++o) qs[o] = fmaf(ai, sW[i * 16 + o], qs[o]);
    }
    float qv[24];
    #pragma unroll
    for (int k = 0; k < 24; ++k) qv[k] = 0.f;
    #pragma unroll 1
    for (int i = 0; i < 8; ++i) {
        float a0 = x[16 + 3*i + 0], a1 = x[16 + 3*i + 1], a2 = x[16 + 3*i + 2];
        #pragma unroll
        for (int o = 0; o < 8; ++o) {
            float wv = sW[256 + i * 8 + o];
            qv[o*3+0] = fmaf(a0, wv, qv[o*3+0]);
            qv[o*3+1] = fmaf(a1, wv, qv[o*3+1]);
            qv[o*3+2] = fmaf(a2, wv, qv[o*3+2]);
        }
    }
    float* qp = g_q + (size_t)n * 40;
    #pragma unroll
    for (int o = 0; o < 16; ++o) qp[o] = qs[o];
    #pragma unroll
    for (int k = 0; k < 24; ++k) qp[16 + k] = qv[k];
}

// ---- direct bucket CSR: one privatized atomic pass, no scan ----
__global__ __launch_bounds__(256) void k_bucket(const int* __restrict__ ei) {
    int e = blockIdx.x * 256 + threadIdx.x;
    if (e >= NEDGES) return;
    int src = ei[NEDGES + e];
    int sl = blockIdx.x & 7;
    u32 p = atomicAdd(&g_cnt8[sl * NNODES + src], 1u);
    if (p < 16u) g_bucket[(size_t)src * 128 + sl * 16 + p] = e;
}

// ========== fused edge kernel: barrier-free, wave-independent M-split ==========
// 64 edges/block, 4 waves; wave w owns edges [w*16, w*16+16) end-to-end.
// EF fragments live in registers (loaded once, reused by both k and v passes).
#define A1S 40    // LDS row stride in halves (80 B)
#define ACCS 41   // accbuf row stride in floats

__global__ __launch_bounds__(256, 3) void k_edge(
    const void* __restrict__ atom, const void* __restrict__ ef,
    const void* __restrict__ sh, const int* __restrict__ ei,
    void* __restrict__ out) {
    __shared__ __align__(16) float smF[91 * 64];       // TP factor table [row][edge]
    __shared__ __align__(16) h16   smA2h[64 * A1S];    // H hi fp16 [edge][32]
    __shared__ __align__(16) h16   smA2l[64 * A1S];
    __shared__ __align__(16) float smAcc[64 * ACCS];   // per-edge out rows [edge][40]

    const int f32 = g_isf32;
    const int t = threadIdx.x;
    const int w = t >> 6, lane = t & 63;
    const int quad = lane >> 4, c = lane & 15;
    const int eb = blockIdx.x * 64;
    const int slice = blockIdx.x & 7;

    // ---- folded passthrough copy of edge_features -> output part 1 ----
    if (f32) {
        const uint4* s = (const uint4*)ef;
        uint4* d = (uint4*)((char*)out + 1600000u);
        size_t i = (size_t)blockIdx.x * 512 + t;
        d[i] = s[i]; d[i + 256] = s[i + 256];
    } else {
        const uint4* s = (const uint4*)ef;
        uint4* d = (uint4*)((char*)out + 800000u);
        size_t i = (size_t)blockIdx.x * 256 + t;
        d[i] = s[i];
    }

    // ---- EF fragment -> registers (per-lane own A-fragment; shared by both passes) ----
    half8 efh, efl;
    {
        const size_t base = (size_t)(eb + w * 16 + c) * 32 + quad * 8;
        h16 th, tl;
        if (f32) {
            const float4* ep = (const float4*)((const float*)ef + base);
            float4 v0 = ep[0], v1 = ep[1];
            split2h(v0.x, th, tl); efh[0] = th; efl[0] = tl;
            split2h(v0.y, th, tl); efh[1] = th; efl[1] = tl;
            split2h(v0.z, th, tl); efh[2] = th; efl[2] = tl;
            split2h(v0.w, th, tl); efh[3] = th; efl[3] = tl;
            split2h(v1.x, th, tl); efh[4] = th; efl[4] = tl;
            split2h(v1.y, th, tl); efh[5] = th; efl[5] = tl;
            split2h(v1.z, th, tl); efh[6] = th; efl[6] = tl;
            split2h(v1.w, th, tl); efh[7] = th; efl[7] = tl;
        } else {
            const u16* ep = (const u16*)ef + base;
            #pragma unroll
            for (int j = 0; j < 8; ++j) {
                split2h(bf2f(ep[j]), th, tl);
                efh[j] = th; efl[j] = tl;
            }
        }
    }

    // ---- wave-local staging: lanes 0-15 produce the factor table ----
    if (lane < 16) {
        const int e = w * 16 + lane;
        const int ge = eb + e;
        const int dst = ei[ge];
        float x[40];
        float ss, s0, s1, s2;
        if (f32) {
            const float4* xp = (const float4*)((const float*)atom + (size_t)dst * 40);
            #pragma unroll
            for (int i = 0; i < 10; ++i) {
                float4 v = xp[i];
                x[i*4+0] = v.x; x[i*4+1] = v.y; x[i*4+2] = v.z; x[i*4+3] = v.w;
            }
            float4 s4 = *(const float4*)((const float*)sh + (size_t)ge * 4);
            ss = s4.x; s0 = s4.y; s1 = s4.z; s2 = s4.w;
        } else {
            #pragma unroll
            for (int i = 0; i < 40; ++i) x[i] = bf2f(((const u16*)atom)[(size_t)dst * 40 + i]);
            ss = bf2f(((const u16*)sh)[(size_t)ge*4+0]);
            s0 = bf2f(((const u16*)sh)[(size_t)ge*4+1]);
            s1 = bf2f(((const u16*)sh)[(size_t)ge*4+2]);
            s2 = bf2f(((const u16*)sh)[(size_t)ge*4+3]);
        }
        #pragma unroll
        for (int i = 0; i < 16; ++i) {
            smF[i * 64 + e] = x[i] * ss;          // fb1 rows 0-15
            smF[(24 + i) * 64 + e] = x[i];        // fb3 rows 24-39
        }
        #pragma unroll
        for (int i = 0; i < 8; ++i) {
            float a0 = x[16+3*i], a1 = x[17+3*i], a2 = x[18+3*i];
            smF[(16 + i) * 64 + e] = C110 * (a0*s0 + a1*s1 + a2*s2);  // fb2 16-23
            smF[(40 + i) * 64 + e] = a0 * ss;                          // fb4 40-63
            smF[(48 + i) * 64 + e] = a1 * ss;
            smF[(56 + i) * 64 + e] = a2 * ss;
            smF[(64 + i) * 64 + e] = C111 * (a1*s2 - a2*s1);           // fb5 64-87
            smF[(72 + i) * 64 + e] = C111 * (a2*s0 - a0*s2);
            smF[(80 + i) * 64 + e] = C111 * (a0*s1 - a1*s0);
        }
        smF[88*64 + e] = s0; smF[89*64 + e] = s1; smF[90*64 + e] = s2;  // sv 88-90
    }
    // NO __syncthreads: all LDS rows are produced and consumed by the same wave.

    const int e0 = w * 16 + quad * 4;  // this lane's 4 edge-rows (local)
    const int o = c & 7, ch = c >> 3;
    const int el = lane >> 2, part = lane & 3;  // epilogue mapping

    #pragma unroll 1
    for (int p = 0; p < 2; ++p) {
        const h16* w1h = p ? g_w1hv : g_w1hk;
        const h16* w1l = p ? g_w1lv : g_w1lk;
        const h16* w2  = p ? g_w2v  : g_w2k;
        const float* b1 = p ? g_b1v : g_b1k;
        const float* b2 = p ? g_b2v : g_b2k;

        // ---- GEMM1: H = relu(EF @ W1 + b1), ~fp32-exact (3 MFMA) ----
        #pragma unroll
        for (int nt = 0; nt < 2; ++nt) {
            half8 bh = *(const half8*)(w1h + (nt*16 + c) * 32 + quad * 8);
            half8 bl = *(const half8*)(w1l + (nt*16 + c) * 32 + quad * 8);
            f32x4 acc = {0.f, 0.f, 0.f, 0.f};
            acc = __builtin_amdgcn_mfma_f32_16x16x32_f16(efl, bh, acc, 0, 0, 0);
            acc = __builtin_amdgcn_mfma_f32_16x16x32_f16(efh, bl, acc, 0, 0, 0);
            acc = __builtin_amdgcn_mfma_f32_16x16x32_f16(efh, bh, acc, 0, 0, 0);
            float bias = b1[nt*16 + c];
            #pragma unroll
            for (int r = 0; r < 4; ++r) {
                float hv = fmaxf(acc[r] + bias, 0.f);
                split2h(hv, smA2h[(w*16 + quad*4 + r) * A1S + nt*16 + c],
                            smA2l[(w*16 + quad*4 + r) * A1S + nt*16 + c]);
            }
        }

        // ---- GEMM2 + fused TP: split-A x single-B (2 MFMA/tile) ----
        half8 afh = *(const half8*)(smA2h + (w*16 + c) * A1S + quad * 8);
        half8 afl = *(const half8*)(smA2l + (w*16 + c) * A1S + quad * 8);

        float aS[4] = {0.f,0.f,0.f,0.f};
        float aT[4] = {0.f,0.f,0.f,0.f};
        float aV[12] = {0.f,0.f,0.f,0.f,0.f,0.f,0.f,0.f,0.f,0.f,0.f,0.f};

        // blocks 1+2: tiles 0..23, f row = nt, out_s col = c
        #pragma unroll 4
        for (int nt = 0; nt < 24; ++nt) {
            half8 b = *(const half8*)(w2 + (nt*16 + c) * 32 + quad * 8);
            float bb = b2[nt*16 + c];
            f32x4 C = {0.f,0.f,0.f,0.f};
            C = __builtin_amdgcn_mfma_f32_16x16x32_f16(afl, b, C, 0, 0, 0);
            C = __builtin_amdgcn_mfma_f32_16x16x32_f16(afh, b, C, 0, 0, 0);
            f32x4 f = *(const f32x4*)(smF + nt * 64 + e0);
            #pragma unroll
            for (int r = 0; r < 4; ++r) aS[r] = fmaf(C[r] + bb, f[r], aS[r]);
        }
        // block 3: tiles 24..31, i = 2*(nt-24)+ch, f row = 24+i -> t3 partial
        #pragma unroll 4
        for (int nt = 24; nt < 32; ++nt) {
            half8 b = *(const half8*)(w2 + (nt*16 + c) * 32 + quad * 8);
            float bb = b2[nt*16 + c];
            f32x4 C = {0.f,0.f,0.f,0.f};
            C = __builtin_amdgcn_mfma_f32_16x16x32_f16(afl, b, C, 0, 0, 0);
            C = __builtin_amdgcn_mfma_f32_16x16x32_f16(afh, b, C, 0, 0, 0);
            f32x4 f = *(const f32x4*)(smF + (24 + 2*(nt-24) + ch) * 64 + e0);
            #pragma unroll
            for (int r = 0; r < 4; ++r) aT[r] = fmaf(C[r] + bb, f[r], aT[r]);
        }
        // block 4: tiles 32..35, f rows 40+d*8+i
        #pragma unroll 2
        for (int nt = 32; nt < 36; ++nt) {
            half8 b = *(const half8*)(w2 + (nt*16 + c) * 32 + quad * 8);
            float bb = b2[nt*16 + c];
            f32x4 C = {0.f,0.f,0.f,0.f};
            C = __builtin_amdgcn_mfma_f32_16x16x32_f16(afl, b, C, 0, 0, 0);
            C = __builtin_amdgcn_mfma_f32_16x16x32_f16(afh, b, C, 0, 0, 0);
            const int i = 2*(nt-32) + ch;
            #pragma unroll
            for (int d = 0; d < 3; ++d) {
                f32x4 f = *(const f32x4*)(smF + (40 + d*8 + i) * 64 + e0);
                #pragma unroll
                for (int r = 0; r < 4; ++r) aV[d*4+r] = fmaf(C[r] + bb, f[r], aV[d*4+r]);
            }
        }
        // block 5: tiles 36..39, f rows 64+d*8+i
        #pragma unroll 2
        for (int nt = 36; nt < 40; ++nt) {
            half8 b = *(const half8*)(w2 + (nt*16 + c) * 32 + quad * 8);
            float bb = b2[nt*16 + c];
            f32x4 C = {0.f,0.f,0.f,0.f};
            C = __builtin_amdgcn_mfma_f32_16x16x32_f16(afl, b, C, 0, 0, 0);
            C = __builtin_amdgcn_mfma_f32_16x16x32_f16(afh, b, C, 0, 0, 0);
            const int i = 2*(nt-36) + ch;
            #pragma unroll
            for (int d = 0; d < 3; ++d) {
                f32x4 f = *(const f32x4*)(smF + (64 + d*8 + i) * 64 + e0);
                #pragma unroll
                for (int r = 0; r < 4; ++r) aV[d*4+r] = fmaf(C[r] + bb, f[r], aV[d*4+r]);
            }
        }

        // ---- flush: out_s direct; out_v via intra-wave shuffle (c <-> c+8) ----
        #pragma unroll
        for (int r = 0; r < 4; ++r) smAcc[(e0 + r) * ACCS + c] = aS[r];
        #pragma unroll
        for (int r = 0; r < 4; ++r) aT[r] += __shfl_xor(aT[r], 8);
        #pragma unroll
        for (int d = 0; d < 3; ++d)
            #pragma unroll
            for (int r = 0; r < 4; ++r) aV[d*4+r] += __shfl_xor(aV[d*4+r], 8);
        if (ch == 0) {
            #pragma unroll
            for (int d = 0; d < 3; ++d) {
                f32x4 sv = *(const f32x4*)(smF + (88 + d) * 64 + e0);
                #pragma unroll
                for (int r = 0; r < 4; ++r)
                    smAcc[(e0 + r) * ACCS + 16 + o*3 + d] = aV[d*4+r] + aT[r] * sv[r];
            }
        }

        // ---- epilogue (wave-local, 4 lanes per edge) ----
        const int ge2 = eb + w * 16 + el;
        const float* ap = smAcc + (w * 16 + el) * ACCS + part * 10;
        if (p == 0) {
            const int src = ei[NEDGES + ge2];
            const float* qp = g_q + (size_t)src * 40 + part * 10;
            float partial = 0.f;
            #pragma unroll
            for (int d2 = 0; d2 < 10; ++d2) partial = fmaf(qp[d2], ap[d2], partial);
            partial += __shfl_xor(partial, 1);
            partial += __shfl_xor(partial, 2);
            if (part == 0) {
                g_attn[ge2] = partial;
                atomicMax(&g_m8[slice * NNODES + src], encf(partial));
            }
        } else {
            float* vb = g_vbuf + (size_t)ge2 * 40 + part * 10;
            #pragma unroll
            for (int d2 = 0; d2 < 10; ++d2) vb[d2] = ap[d2];
        }
    }
}

// ---- fused: per-node softmax gather + x = atom + upd/den + batchnorm stats ----
__global__ __launch_bounds__(256) void k_post(const void* __restrict__ atom) {
    __shared__ float part[40];
    const int f32 = g_isf32;
    const int node = blockIdx.x * 4 + (threadIdx.x >> 6);   // 2500*4 == NNODES exactly
    const int lane = threadIdx.x & 63;
    if (threadIdx.x < 40) part[threadIdx.x] = 0.f;
    __syncthreads();

    float m = -__builtin_huge_valf();
    #pragma unroll
    for (int s = 0; s < 8; ++s) m = fmaxf(m, decf(g_m8[s * NNODES + node]));

    float den = 0.f, acc = 0.f;
    #pragma unroll 1
    for (int s = 0; s < 8; ++s) {
        u32 cn = g_cnt8[s * NNODES + node];
        if (cn > 16u) cn = 16u;
        const int* bk = g_bucket + (size_t)node * 128 + s * 16;
        for (u32 j = 0; j < cn; ++j) {
            int e = bk[j];
            float pex = expf(fminf(g_attn[e] - m, 0.f));
            den += pex;   // pex is lane-invariant: every lane holds the full denominator
            if (lane < 40) acc = fmaf(pex, g_vbuf[(size_t)e * 40 + lane], acc);
        }
    }
    float inv = (den > 0.f) ? 1.f / den : 0.f;
    float xv = 0.f;
    if (lane < 40) {
        xv = ldx(atom, (size_t)node * 40 + lane, f32) + acc * inv;
        g_x[(size_t)node * 40 + lane] = xv;
    }
    // stats: lanes 0-15 scalar sums; vector norms from lane triplets
    if (lane < 16) {
        atomicAdd(&part[lane], xv);
        atomicAdd(&part[16 + lane], xv * xv);
    }
    float sq = xv * xv;
    float tri = sq + __shfl_down(sq, 1) + __shfl_down(sq, 2);
    if (lane >= 16 && lane < 40 && ((lane - 16) % 3 == 0))
        atomicAdd(&part[32 + (lane - 16) / 3], tri);
    __syncthreads();
    if (threadIdx.x < 40) atomicAdd(&g_stats[threadIdx.x], part[threadIdx.x]);
}

__global__ void k_final(const void* __restrict__ bws, const void* __restrict__ bbs,
                        const void* __restrict__ bwv) {
    const int f32 = g_isf32;
    int t = threadIdx.x;
    const float invN = 1.f / (float)NNODES;
    if (t < 16) {
        float mu = g_stats[t] * invN;
        float var = fmaxf(g_stats[16 + t] * invN - mu * mu, 0.f);
        float isd = 1.f / sqrtf(var + 1e-5f);
        float sc = ldx(bws, t, f32) * isd;
        g_par[t] = sc;
        g_par[16 + t] = ldx(bbs, t, f32) - mu * sc;
    } else if (t >= 32 && t < 40) {
        int i = t - 32;
        float norm = g_stats[32 + i] * (invN / 3.f);
        g_par[32 + i] = ldx(bwv, i, f32) / sqrtf(norm + 1e-5f);
    }
}

__global__ __launch_bounds__(256) void k_out(void* __restrict__ out) {
    const int f32 = g_isf32;
    int n = blockIdx.x * 256 + threadIdx.x;
    if (n >= NNODES) return;
    const float4* xp4 = (const float4*)(g_x + (size_t)n * 40);
    float xp[40];
    #pragma unroll
    for (int c = 0; c < 10; ++c) {
        float4 v = xp4[c];
        xp[c*4+0] = v.x; xp[c*4+1] = v.y; xp[c*4+2] = v.z; xp[c*4+3] = v.w;
    }
    float res[40];
    #pragma unroll
    for (int c = 0; c < 16; ++c) res[c] = xp[c] * g_par[c] + g_par[16 + c];
    #pragma unroll
    for (int i = 0; i < 8; ++i) {
        float s = g_par[32 + i];
        res[16+3*i+0] = xp[16+3*i+0] * s;
        res[16+3*i+1] = xp[16+3*i+1] * s;
        res[16+3*i+2] = xp[16+3*i+2] * s;
    }
    if (f32) {
        float4* op = (float4*)((float*)out + (size_t)n * 40);
        #pragma unroll
        for (int c = 0; c < 10; ++c)
            op[c] = make_float4(res[c*4+0], res[c*4+1], res[c*4+2], res[c*4+3]);
    } else {
        uint4* op = (uint4*)((u16*)out + (size_t)n * 40);
        #pragma unroll
        for (int c = 0; c < 5; ++c) {
            uint4 r;
            r.x = pack2(res[c*8+0], res[c*8+1]);
            r.y = pack2(res[c*8+2], res[c*8+3]);
            r.z = pack2(res[c*8+4], res[c*8+5]);
            r.w = pack2(res[c*8+6], res[c*8+7]);
            op[c] = r;
        }
    }
}

extern "C" void kernel_launch(void* const* d_in, const int* in_sizes, int n_in,
                              void* d_out, int out_size, void* d_ws, size_t ws_size,
                              hipStream_t stream) {
    const void* atom = d_in[0];
    const void* ef   = d_in[1];
    const void* sh   = d_in[2];
    const void* Wqs  = d_in[3];
    const void* Wqv  = d_in[4];
    const void* kw1  = d_in[5];
    const void* kb1  = d_in[6];
    const void* kw2  = d_in[7];
    const void* kb2  = d_in[8];
    const void* vw1  = d_in[9];
    const void* vb1  = d_in[10];
    const void* vw2  = d_in[11];
    const void* vb2  = d_in[12];
    const void* bws  = d_in[13];
    const void* bbs  = d_in[14];
    const void* bwv  = d_in[15];
    const int*  ei   = (const int*)d_in[16];

    k_init<<<320, 256, 0, stream>>>((const u16*)atom);
    k_prep<<<80, 256, 0, stream>>>(kw1, kb1, kw2, kb2, vw1, vb1, vw2, vb2);
    k_q<<<40, 256, 0, stream>>>(atom, Wqs, Wqv);
    k_bucket<<<625, 256, 0, stream>>>(ei);
    k_edge<<<2500, 256, 0, stream>>>(atom, ef, sh, ei, d_out);
    k_post<<<2500, 256, 0, stream>>>(atom);
    k_final<<<1, 64, 0, stream>>>(bws, bbs, bwv);
    k_out<<<40, 256, 0, stream>>>(d_out);
}